// Round 4
// baseline (242.489 us; speedup 1.0000x reference)
//
#include <hip/hip_runtime.h>
#include <math.h>

#define T_DIM 2048
#define B_DIM 8
#define D_DIM 1024
#define N_DIM 64
#define NCHUNK 16
#define CHUNK_LEN 128              // T_DIM / NCHUNK
#define DECAY 0.9f
#define DECAY_L 1.3900845237714473e-06f  // 0.9^128 (double-derived)
#define EPS 1e-8f
#define RADIUS 0.5f

typedef __attribute__((ext_vector_type(8))) short short8;   // bf16x8 MFMA frag
typedef __attribute__((ext_vector_type(4))) short short4v;  // 8B LDS write
typedef __attribute__((ext_vector_type(4))) float f32x4;

static __device__ __forceinline__ unsigned short f2bf(float f) {
    unsigned u = __float_as_uint(f);
    u += 0x7FFFu + ((u >> 16) & 1u);          // RNE
    return (unsigned short)(u >> 16);
}
static __device__ __forceinline__ float bf2f(unsigned short h) {
    return __uint_as_float(((unsigned)h) << 16);
}

// ---------------- spectral norm scale (2 blocks: k and v) ----------------
__global__ __launch_bounds__(1024)
void spectral_kernel(const float* __restrict__ Wk,
                     const float* __restrict__ Wv,
                     const float* __restrict__ uk,
                     const float* __restrict__ uv,
                     float* __restrict__ scale_out) {
    const float* W  = (blockIdx.x == 0) ? Wk : Wv;
    const float* u0 = (blockIdx.x == 0) ? uk : uv;
    int tid = threadIdx.x;       // 0..1023 = d
    int lane = tid & 63;
    int wid = tid >> 6;          // 0..15
    __shared__ float u_s[N_DIM];
    __shared__ float v_s[D_DIM];
    __shared__ float t_s[N_DIM];
    __shared__ float red[16];
    __shared__ float bcs;
    if (tid < N_DIM) u_s[tid] = u0[tid];
    __syncthreads();
    for (int iter = 0; iter < 3; ++iter) {
        float acc = 0.f;
        #pragma unroll
        for (int nn = 0; nn < N_DIM; ++nn)
            acc += W[nn * D_DIM + tid] * u_s[nn];
        float ss = acc * acc;
        #pragma unroll
        for (int o = 32; o > 0; o >>= 1) ss += __shfl_xor(ss, o, 64);
        if (lane == 0) red[wid] = ss;
        __syncthreads();
        if (tid == 0) {
            float tot = 0.f;
            #pragma unroll
            for (int w2 = 0; w2 < 16; ++w2) tot += red[w2];
            bcs = 1.0f / (sqrtf(tot) + EPS);
        }
        __syncthreads();
        v_s[tid] = acc * bcs;
        __syncthreads();
        #pragma unroll
        for (int rr = 0; rr < 4; ++rr) {
            int r = wid * 4 + rr;
            float a = 0.f;
            #pragma unroll
            for (int e = 0; e < 16; ++e)
                a += W[r * D_DIM + lane + 64 * e] * v_s[lane + 64 * e];
            #pragma unroll
            for (int o = 32; o > 0; o >>= 1) a += __shfl_xor(a, o, 64);
            if (lane == 0) t_s[r] = a;
        }
        __syncthreads();
        if (wid == 0) {
            float uu = t_s[lane];
            float s2 = uu * uu;
            #pragma unroll
            for (int o = 32; o > 0; o >>= 1) s2 += __shfl_xor(s2, o, 64);
            float inv = 1.0f / (sqrtf(__shfl(s2, 0, 64)) + EPS);
            u_s[lane] = uu * inv;
        }
        __syncthreads();
    }
    if (wid == 0) {
        float val = t_s[lane] * u_s[lane];
        #pragma unroll
        for (int o = 32; o > 0; o >>= 1) val += __shfl_xor(val, o, 64);
        if (lane == 0) scale_out[blockIdx.x] = RADIUS / (fabsf(val) + EPS);
    }
}

// ------- build bf16 hi/lo of fused scaled W, stored row-major [c][k] (c: k|v|q) -------
__global__ __launch_bounds__(256)
void build_wt_kernel(const float* __restrict__ Wk,
                     const float* __restrict__ Wv,
                     const float* __restrict__ Wq,
                     const float* __restrict__ scale,
                     unsigned short* __restrict__ Wth,
                     unsigned short* __restrict__ Wtl) {
    int c = blockIdx.x;           // 0..191
    int t = threadIdx.x;          // 0..255, 4 elems each
    const float* src;
    float sc;
    if (c < 64)       { src = Wk + (size_t)c * D_DIM;         sc = scale[0]; }
    else if (c < 128) { src = Wv + (size_t)(c - 64) * D_DIM;  sc = scale[1]; }
    else              { src = Wq + (size_t)(c - 128) * D_DIM; sc = 1.0f; }
    float4 w = *(const float4*)(src + t * 4);
    float vals[4] = {w.x * sc, w.y * sc, w.z * sc, w.w * sc};
    unsigned short h[4], l[4];
    #pragma unroll
    for (int e = 0; e < 4; ++e) {
        h[e] = f2bf(vals[e]);
        l[e] = f2bf(vals[e] - bf2f(h[e]));
    }
    size_t base = (size_t)c * D_DIM + t * 4;
    *(ushort4*)(Wth + base) = make_ushort4(h[0], h[1], h[2], h[3]);
    *(ushort4*)(Wtl + base) = make_ushort4(l[0], l[1], l[2], l[3]);
}

// ------------- projections via split-bf16 MFMA: kvq = x . Wt^T -------------
// BM=32 rows, 512 blocks, 8 waves: wave = (mt = wv>>2, ntg = wv&3) -> 1 M-tile x 3 N-tiles.
// 2-deep x prefetch: load s+2 to regs at step s; write s+1 regs->LDS after MFMAs.
#define PBM 32
#define PBK 64
__global__ __launch_bounds__(512)
void proj_mfma_kernel(const float* __restrict__ x,
                      const unsigned short* __restrict__ Wth,
                      const unsigned short* __restrict__ Wtl,
                      float* __restrict__ kvq) {
    __shared__ __align__(16) unsigned short lds[2][2][PBM * PBK];  // 16 KB
    int tid = threadIdx.x;
    int lane = tid & 63;
    int wv = tid >> 6;                 // 0..7
    int mt = wv >> 2;                  // 0..1
    int ntg = wv & 3;                  // 0..3 -> cols [ntg*48, +48)
    int fl15 = lane & 15;
    int flh = lane >> 4;               // 0..3
    int rowBase = blockIdx.x * PBM;

    // staging: thread t handles row t>>4, 4 floats at col (t&15)*4
    int r_st = tid >> 4;
    const float* xptr = x + (size_t)(rowBase + r_st) * D_DIM + (tid & 15) * 4;
    int wr_off = (r_st * 128 + (tid & 15) * 8) ^ ((r_st & 7) << 4);  // bytes

    // B-frag base pointers (lane-resolved)
    size_t boff = (size_t)(ntg * 48 + fl15) * D_DIM + flh * 8;
    const unsigned short* bph = Wth + boff;
    const unsigned short* bpl = Wtl + boff;

    f32x4 acc[3];
    #pragma unroll
    for (int nt = 0; nt < 3; ++nt) acc[nt] = (f32x4)(0.f);

    // pipeline regs
    float4 A = *(const float4*)(xptr);          // s=0
    {
        float v[4] = {A.x, A.y, A.z, A.w};
        short4v hv, lv;
        #pragma unroll
        for (int e = 0; e < 4; ++e) {
            unsigned short hh = f2bf(v[e]);
            hv[e] = (short)hh;
            lv[e] = (short)f2bf(v[e] - bf2f(hh));
        }
        *(short4v*)((char*)&lds[0][0][0] + wr_off) = hv;
        *(short4v*)((char*)&lds[0][1][0] + wr_off) = lv;
    }
    float4 Bv = *(const float4*)(xptr + PBK);   // s=1
    __syncthreads();

    for (int s = 0; s < 16; ++s) {
        // issue 2-ahead x load
        if (s < 14) A = *(const float4*)(xptr + (s + 2) * PBK);
        // B fragments for this K-step (12 x 16B, L2-hit)
        int k0 = s * PBK;
        short8 bh[2][3], bl[2][3];
        #pragma unroll
        for (int kh = 0; kh < 2; ++kh)
            #pragma unroll
            for (int nt = 0; nt < 3; ++nt) {
                bh[kh][nt] = *(const short8*)(bph + (size_t)nt * 16 * D_DIM + k0 + kh * 32);
                bl[kh][nt] = *(const short8*)(bpl + (size_t)nt * 16 * D_DIM + k0 + kh * 32);
            }
        const char* ldsH = (const char*)&lds[s & 1][0][0];
        const char* ldsL = (const char*)&lds[s & 1][1][0];
        int row = mt * 16 + fl15;
        #pragma unroll
        for (int kh = 0; kh < 2; ++kh) {
            int off = (row * 128 + kh * 64 + flh * 16) ^ ((row & 7) << 4);
            short8 ah = *(const short8*)(ldsH + off);
            short8 al = *(const short8*)(ldsL + off);
            #pragma unroll
            for (int nt = 0; nt < 3; ++nt) {
                acc[nt] = __builtin_amdgcn_mfma_f32_16x16x32_bf16(ah, bh[kh][nt], acc[nt], 0, 0, 0);
                acc[nt] = __builtin_amdgcn_mfma_f32_16x16x32_bf16(ah, bl[kh][nt], acc[nt], 0, 0, 0);
                acc[nt] = __builtin_amdgcn_mfma_f32_16x16x32_bf16(al, bh[kh][nt], acc[nt], 0, 0, 0);
            }
        }
        // write s+1 tile from regs into the other buffer
        if (s < 15) {
            float v[4] = {Bv.x, Bv.y, Bv.z, Bv.w};
            short4v hv, lv;
            #pragma unroll
            for (int e = 0; e < 4; ++e) {
                unsigned short hh = f2bf(v[e]);
                hv[e] = (short)hh;
                lv[e] = (short)f2bf(v[e] - bf2f(hh));
            }
            *(short4v*)((char*)&lds[(s + 1) & 1][0][0] + wr_off) = hv;
            *(short4v*)((char*)&lds[(s + 1) & 1][1][0] + wr_off) = lv;
        }
        Bv = A;   // A's data (s+2) becomes next step's write payload
        __syncthreads();
    }

    // epilogue: C/D layout col=lane&15, row=(lane>>4)*4+reg  [m89]
    #pragma unroll
    for (int nt = 0; nt < 3; ++nt) {
        int col = ntg * 48 + nt * 16 + fl15;
        #pragma unroll
        for (int r = 0; r < 4; ++r) {
            int row = rowBase + mt * 16 + flh * 4 + r;
            kvq[(size_t)row * 192 + col] = acc[nt][r];
        }
    }
}

// ------------- fused scan: one block per (b,i); wave c = chunk c -------------
// Phase 1: chunk-local final states -> LDS. syncthreads.
// Phase 2: fold carry from LDS, replay chunk writing S_all + silu output.
__global__ __launch_bounds__(1024)
void scan_fused_kernel(const float* __restrict__ kvq,
                       const float* __restrict__ S0,
                       float* __restrict__ out,      // [T,B,n]
                       float* __restrict__ S_all) {  // [T+1,B,n,n]
    __shared__ float locals[NCHUNK][N_DIM];
    __shared__ __align__(16) float P[NCHUNK][16][68];
    int b = blockIdx.x >> 6;
    int i = blockIdx.x & 63;
    int c = threadIdx.x >> 6;         // chunk = wave
    int j = threadIdx.x & 63;
    int tl = j & 15;
    int part = j >> 4;
    int t0 = c * CHUNK_LEN;

    // S0 row copy (wave 0)
    if (c == 0)
        S_all[(size_t)b * 4096 + (size_t)i * 64 + j] = S0[((size_t)b * 64 + i) * 64 + j];

    // phase 1: local scan (zero init)
    {
        float s = 0.f;
        for (int t = t0; t < t0 + CHUNK_LEN; ++t) {
            const float* base = kvq + (size_t)(t * B_DIM + b) * 192;
            s = __builtin_fmaf(DECAY, s, base[64 + i] * base[j]);
        }
        locals[c][j] = s;
    }
    __syncthreads();

    // carry for this chunk
    float s = 0.f;
    for (int cp = 0; cp < c; ++cp)
        s = __builtin_fmaf(DECAY_L, s, locals[cp][j]);

    // phase 2: replay with carry
    for (int tb = 0; tb < CHUNK_LEN; tb += 16) {
        #pragma unroll
        for (int u = 0; u < 16; ++u) {
            int t = t0 + tb + u;
            const float* base = kvq + (size_t)(t * B_DIM + b) * 192;
            float k = base[j];
            float v = base[64 + i];
            float q = base[128 + j];
            s = __builtin_fmaf(DECAY, s, v * k);
            S_all[((size_t)(t + 1) * B_DIM + b) * 4096 + (size_t)i * 64 + j] = s;
            P[c][u][j] = s * q;
        }
        float acc = 0.f;
        #pragma unroll
        for (int rd = 0; rd < 4; ++rd) {
            const float4 a = *(const float4*)&P[c][tl][part * 16 + rd * 4];
            acc += (a.x + a.y) + (a.z + a.w);
        }
        acc += __shfl_xor(acc, 16, 64);
        acc += __shfl_xor(acc, 32, 64);
        if (part == 0) {
            int t = t0 + tb + tl;
            float sg = 1.0f / (1.0f + __expf(-acc));
            out[(t * B_DIM + b) * 64 + i] = acc * acc * sg;
        }
    }
}

extern "C" void kernel_launch(void* const* d_in, const int* in_sizes, int n_in,
                              void* d_out, int out_size, void* d_ws, size_t ws_size,
                              hipStream_t stream) {
    const float* x  = (const float*)d_in[0];
    const float* S0 = (const float*)d_in[1];
    const float* Wk = (const float*)d_in[2];
    const float* Wv = (const float*)d_in[3];
    const float* Wq = (const float*)d_in[4];
    const float* uk = (const float*)d_in[5];
    const float* uv = (const float*)d_in[6];

    float* out   = (float*)d_out;                              // [T,B,n]
    float* S_all = out + (size_t)T_DIM * B_DIM * N_DIM;        // [T+1,B,n,n]

    float* ws    = (float*)d_ws;
    float* scale = ws;                                   // 2 floats (pad 64)
    float* kvq   = ws + 64;                              // 16384*192
    unsigned short* Wth = (unsigned short*)(kvq + (size_t)16384 * 192);  // 192*1024
    unsigned short* Wtl = Wth + (size_t)192 * D_DIM;

    spectral_kernel<<<2, 1024, 0, stream>>>(Wk, Wv, uk, uv, scale);
    build_wt_kernel<<<192, 256, 0, stream>>>(Wk, Wv, Wq, scale, Wth, Wtl);
    proj_mfma_kernel<<<T_DIM * B_DIM / PBM, 512, 0, stream>>>(x, Wth, Wtl, kvq);
    scan_fused_kernel<<<B_DIM * N_DIM, 1024, 0, stream>>>(kvq, S0, out, S_all);
}

// Round 5
// 228.299 us; speedup vs baseline: 1.0622x; 1.0622x over previous
//
#include <hip/hip_runtime.h>
#include <math.h>

#define T_DIM 2048
#define B_DIM 8
#define D_DIM 1024
#define N_DIM 64
#define NCHUNK 16
#define CHUNK_LEN 128              // T_DIM / NCHUNK
#define DECAY 0.9f
#define DECAY_L 1.3900845237714473e-06f  // 0.9^128 (double-derived)
#define EPS 1e-8f
#define RADIUS 0.5f

typedef __attribute__((ext_vector_type(8))) short short8;   // bf16x8 MFMA frag
typedef __attribute__((ext_vector_type(4))) float f32x4;

static __device__ __forceinline__ unsigned short f2bf(float f) {
    unsigned u = __float_as_uint(f);
    u += 0x7FFFu + ((u >> 16) & 1u);          // RNE
    return (unsigned short)(u >> 16);
}
static __device__ __forceinline__ float bf2f(unsigned short h) {
    return __uint_as_float(((unsigned)h) << 16);
}

// ---------------- spectral norm scale (2 blocks: k and v) ----------------
__global__ __launch_bounds__(1024)
void spectral_kernel(const float* __restrict__ Wk,
                     const float* __restrict__ Wv,
                     const float* __restrict__ uk,
                     const float* __restrict__ uv,
                     float* __restrict__ scale_out) {
    const float* W  = (blockIdx.x == 0) ? Wk : Wv;
    const float* u0 = (blockIdx.x == 0) ? uk : uv;
    int tid = threadIdx.x;       // 0..1023 = d
    int lane = tid & 63;
    int wid = tid >> 6;          // 0..15
    __shared__ float u_s[N_DIM];
    __shared__ float v_s[D_DIM];
    __shared__ float t_s[N_DIM];
    __shared__ float red[16];
    __shared__ float bcs;
    if (tid < N_DIM) u_s[tid] = u0[tid];
    __syncthreads();
    for (int iter = 0; iter < 3; ++iter) {
        float acc = 0.f;
        #pragma unroll
        for (int nn = 0; nn < N_DIM; ++nn)
            acc += W[nn * D_DIM + tid] * u_s[nn];
        float ss = acc * acc;
        #pragma unroll
        for (int o = 32; o > 0; o >>= 1) ss += __shfl_xor(ss, o, 64);
        if (lane == 0) red[wid] = ss;
        __syncthreads();
        if (tid == 0) {
            float tot = 0.f;
            #pragma unroll
            for (int w2 = 0; w2 < 16; ++w2) tot += red[w2];
            bcs = 1.0f / (sqrtf(tot) + EPS);
        }
        __syncthreads();
        v_s[tid] = acc * bcs;
        __syncthreads();
        #pragma unroll
        for (int rr = 0; rr < 4; ++rr) {
            int r = wid * 4 + rr;
            float a = 0.f;
            #pragma unroll
            for (int e = 0; e < 16; ++e)
                a += W[r * D_DIM + lane + 64 * e] * v_s[lane + 64 * e];
            #pragma unroll
            for (int o = 32; o > 0; o >>= 1) a += __shfl_xor(a, o, 64);
            if (lane == 0) t_s[r] = a;
        }
        __syncthreads();
        if (wid == 0) {
            float uu = t_s[lane];
            float s2 = uu * uu;
            #pragma unroll
            for (int o = 32; o > 0; o >>= 1) s2 += __shfl_xor(s2, o, 64);
            float inv = 1.0f / (sqrtf(__shfl(s2, 0, 64)) + EPS);
            u_s[lane] = uu * inv;
        }
        __syncthreads();
    }
    if (wid == 0) {
        float val = t_s[lane] * u_s[lane];
        #pragma unroll
        for (int o = 32; o > 0; o >>= 1) val += __shfl_xor(val, o, 64);
        if (lane == 0) scale_out[blockIdx.x] = RADIUS / (fabsf(val) + EPS);
    }
}

// ------- build bf16 hi/lo of fused scaled W, stored row-major [c][k] (c: k|v|q) -------
__global__ __launch_bounds__(256)
void build_wt_kernel(const float* __restrict__ Wk,
                     const float* __restrict__ Wv,
                     const float* __restrict__ Wq,
                     const float* __restrict__ scale,
                     unsigned short* __restrict__ Wth,
                     unsigned short* __restrict__ Wtl) {
    int c = blockIdx.x;           // 0..191
    int t = threadIdx.x;          // 0..255, 4 elems each
    const float* src;
    float sc;
    if (c < 64)       { src = Wk + (size_t)c * D_DIM;         sc = scale[0]; }
    else if (c < 128) { src = Wv + (size_t)(c - 64) * D_DIM;  sc = scale[1]; }
    else              { src = Wq + (size_t)(c - 128) * D_DIM; sc = 1.0f; }
    float4 w = *(const float4*)(src + t * 4);
    float vals[4] = {w.x * sc, w.y * sc, w.z * sc, w.w * sc};
    unsigned short h[4], l[4];
    #pragma unroll
    for (int e = 0; e < 4; ++e) {
        h[e] = f2bf(vals[e]);
        l[e] = f2bf(vals[e] - bf2f(h[e]));
    }
    size_t base = (size_t)c * D_DIM + t * 4;
    *(ushort4*)(Wth + base) = make_ushort4(h[0], h[1], h[2], h[3]);
    *(ushort4*)(Wtl + base) = make_ushort4(l[0], l[1], l[2], l[3]);
}

// ------------- projections via split-bf16 MFMA: kvq = x . Wt^T -------------
// Barrier-free, LDS-free: A-frags loaded from fp32 x and converted in-register;
// B-frags from L2-resident Wth/Wtl. Compiler free to pipeline across K-steps.
// BM=32 rows/block, 512 blocks, 4 waves: wave wv owns cols [wv*48,+48), all 32 rows.
#define PBM 32
#define PBK 64
__global__ __launch_bounds__(256)
void proj_mfma_kernel(const float* __restrict__ x,
                      const unsigned short* __restrict__ Wth,
                      const unsigned short* __restrict__ Wtl,
                      float* __restrict__ kvq) {
    int tid = threadIdx.x;
    int lane = tid & 63;
    int wv = tid >> 6;                 // 0..3 -> cols [wv*48, +48)
    int fl15 = lane & 15;
    int flh = lane >> 4;               // 0..3
    int rowBase = blockIdx.x * PBM;

    // B-frag base (lane-resolved): col wv*48+fl15, k-slice flh*8
    size_t boff = (size_t)(wv * 48 + fl15) * D_DIM + flh * 8;
    const unsigned short* bph = Wth + boff;
    const unsigned short* bpl = Wtl + boff;
    // A base (lane-resolved): row rowBase+fl15 (+mt*16), k-slice flh*8 (+kk*32)
    const float* aptr = x + (size_t)(rowBase + fl15) * D_DIM + flh * 8;

    f32x4 acc[2][3];
    #pragma unroll
    for (int mt = 0; mt < 2; ++mt)
        #pragma unroll
        for (int nt = 0; nt < 3; ++nt) acc[mt][nt] = (f32x4)(0.f);

    for (int s = 0; s < 16; ++s) {
        int k0 = s * PBK;
        // A fragments: 4 frags (2 mt x 2 kk), fp32 -> bf16 hi/lo in-register
        short8 ah[2][2], al[2][2];
        #pragma unroll
        for (int mt = 0; mt < 2; ++mt)
            #pragma unroll
            for (int kk = 0; kk < 2; ++kk) {
                const float* p = aptr + (size_t)mt * 16 * D_DIM + k0 + kk * 32;
                float4 lo = *(const float4*)p;
                float4 hi = *(const float4*)(p + 4);
                float v[8] = {lo.x, lo.y, lo.z, lo.w, hi.x, hi.y, hi.z, hi.w};
                #pragma unroll
                for (int e = 0; e < 8; ++e) {
                    unsigned short hh = f2bf(v[e]);
                    ah[mt][kk][e] = (short)hh;
                    al[mt][kk][e] = (short)f2bf(v[e] - bf2f(hh));
                }
            }
        // B fragments: 12 x 16B L2 loads
        short8 bh[2][3], bl[2][3];
        #pragma unroll
        for (int kk = 0; kk < 2; ++kk)
            #pragma unroll
            for (int nt = 0; nt < 3; ++nt) {
                bh[kk][nt] = *(const short8*)(bph + (size_t)nt * 16 * D_DIM + k0 + kk * 32);
                bl[kk][nt] = *(const short8*)(bpl + (size_t)nt * 16 * D_DIM + k0 + kk * 32);
            }
        #pragma unroll
        for (int kk = 0; kk < 2; ++kk)
            #pragma unroll
            for (int mt = 0; mt < 2; ++mt)
                #pragma unroll
                for (int nt = 0; nt < 3; ++nt) {
                    acc[mt][nt] = __builtin_amdgcn_mfma_f32_16x16x32_bf16(
                        ah[mt][kk], bh[kk][nt], acc[mt][nt], 0, 0, 0);
                    acc[mt][nt] = __builtin_amdgcn_mfma_f32_16x16x32_bf16(
                        ah[mt][kk], bl[kk][nt], acc[mt][nt], 0, 0, 0);
                    acc[mt][nt] = __builtin_amdgcn_mfma_f32_16x16x32_bf16(
                        al[mt][kk], bh[kk][nt], acc[mt][nt], 0, 0, 0);
                }
    }

    // epilogue: C/D layout col=lane&15, row=(lane>>4)*4+reg  [m89]
    #pragma unroll
    for (int mt = 0; mt < 2; ++mt)
        #pragma unroll
        for (int nt = 0; nt < 3; ++nt) {
            int col = wv * 48 + nt * 16 + fl15;
            #pragma unroll
            for (int r = 0; r < 4; ++r) {
                int row = rowBase + mt * 16 + flh * 4 + r;
                kvq[(size_t)row * 192 + col] = acc[mt][nt][r];
            }
        }
}

// ------------- pass 1: chunk-local final states (zero-init) -------------
__global__ void pass1_kernel(const float* __restrict__ kvq,
                             float* __restrict__ local) {
    int w = (blockIdx.x * blockDim.x + threadIdx.x) >> 6;  // wave id: c*512 + b*64 + i
    int j = threadIdx.x & 63;
    int c = w >> 9;
    int rem = w & 511;
    int b = rem >> 6;
    int i = rem & 63;
    float s = 0.f;
    int t0 = c * CHUNK_LEN;
    for (int t = t0; t < t0 + CHUNK_LEN; ++t) {
        const float* base = kvq + (size_t)(t * B_DIM + b) * 192;
        float k = base[j];
        float v = base[64 + i];
        s = DECAY * s + v * k;
    }
    local[(size_t)w * 64 + j] = s;
}

// ------------- chunk-carry scan (16 steps, thread per (b,i,j)) -------------
__global__ void chunkscan_kernel(const float* __restrict__ local,
                                 float* __restrict__ carry) {
    int e = blockIdx.x * blockDim.x + threadIdx.x;   // 0..32767
    float cy = 0.f;
    #pragma unroll
    for (int c = 0; c < NCHUNK; ++c) {
        carry[c * 32768 + e] = cy;
        cy = DECAY_L * cy + local[c * 32768 + e];
    }
}

// ------------- pass 2: full scan with carry, writes S_all[1..T] and output -------------
#define P2_WAVES 4
__global__ __launch_bounds__(256)
void pass2_kernel(const float* __restrict__ kvq,
                  const float* __restrict__ carry,
                  float* __restrict__ out,      // [T,B,n]
                  float* __restrict__ S_all) {  // [T+1,B,n,n]
    __shared__ __align__(16) float P[P2_WAVES][16][68];   // padded: conflict-free reads
    int widL = threadIdx.x >> 6;                 // wave in block
    int j = threadIdx.x & 63;
    int w = blockIdx.x * P2_WAVES + widL;        // global wave id: c*512 + b*64 + i
    int c = w >> 9;
    int rem = w & 511;
    int b = rem >> 6;
    int i = rem & 63;
    int tl = j & 15;          // t-slot this lane reduces
    int part = j >> 4;        // 16-column slice this lane sums

    float s = carry[(size_t)w * 64 + j];
    int t0 = c * CHUNK_LEN;
    for (int tb = 0; tb < CHUNK_LEN; tb += 16) {
        #pragma unroll
        for (int u = 0; u < 16; ++u) {
            int t = t0 + tb + u;
            const float* base = kvq + (size_t)(t * B_DIM + b) * 192;
            float k = base[j];
            float v = base[64 + i];
            float q = base[128 + j];
            s = __builtin_fmaf(DECAY, s, v * k);
            S_all[((size_t)(t + 1) * B_DIM + b) * 4096 + (size_t)i * 64 + j] = s;
            P[widL][u][j] = s * q;
        }
        float acc = 0.f;
        #pragma unroll
        for (int rd = 0; rd < 4; ++rd) {
            const float4 a = *(const float4*)&P[widL][tl][part * 16 + rd * 4];
            acc += (a.x + a.y) + (a.z + a.w);
        }
        acc += __shfl_xor(acc, 16, 64);
        acc += __shfl_xor(acc, 32, 64);
        if (part == 0) {
            int t = t0 + tb + tl;
            float sg = 1.0f / (1.0f + __expf(-acc));
            out[(t * B_DIM + b) * 64 + i] = acc * acc * sg;
        }
    }
}

extern "C" void kernel_launch(void* const* d_in, const int* in_sizes, int n_in,
                              void* d_out, int out_size, void* d_ws, size_t ws_size,
                              hipStream_t stream) {
    const float* x  = (const float*)d_in[0];
    const float* S0 = (const float*)d_in[1];
    const float* Wk = (const float*)d_in[2];
    const float* Wv = (const float*)d_in[3];
    const float* Wq = (const float*)d_in[4];
    const float* uk = (const float*)d_in[5];
    const float* uv = (const float*)d_in[6];

    float* out   = (float*)d_out;                              // [T,B,n]
    float* S_all = out + (size_t)T_DIM * B_DIM * N_DIM;        // [T+1,B,n,n]

    float* ws    = (float*)d_ws;
    float* scale = ws;                                   // 2 floats (pad 64)
    float* kvq   = ws + 64;                              // 16384*192
    unsigned short* Wth = (unsigned short*)(kvq + (size_t)16384 * 192);  // 192*1024
    unsigned short* Wtl = Wth + (size_t)192 * D_DIM;
    float* local = (float*)(Wtl + (size_t)192 * D_DIM);  // 16*32768
    float* carry = local + (size_t)NCHUNK * 32768;       // 16*32768

    spectral_kernel<<<2, 1024, 0, stream>>>(Wk, Wv, uk, uv, scale);
    build_wt_kernel<<<192, 256, 0, stream>>>(Wk, Wv, Wq, scale, Wth, Wtl);
    proj_mfma_kernel<<<T_DIM * B_DIM / PBM, 256, 0, stream>>>(x, Wth, Wtl, kvq);
    pass1_kernel<<<NCHUNK * B_DIM * N_DIM / 4, 256, 0, stream>>>(kvq, local);
    chunkscan_kernel<<<B_DIM * N_DIM * N_DIM / 256, 256, 0, stream>>>(local, carry);
    hipMemcpyAsync(S_all, S0, sizeof(float) * B_DIM * N_DIM * N_DIM,
                   hipMemcpyDeviceToDevice, stream);
    pass2_kernel<<<NCHUNK * B_DIM * N_DIM / 4, 256, 0, stream>>>(kvq, carry, out, S_all);
}

// Round 6
// 189.690 us; speedup vs baseline: 1.2783x; 1.2035x over previous
//
#include <hip/hip_runtime.h>
#include <math.h>

#define T_DIM 2048
#define B_DIM 8
#define D_DIM 1024
#define N_DIM 64
#define NCHUNK 16
#define CHUNK_LEN 128              // T_DIM / NCHUNK
#define DECAY 0.9f
#define DECAY_L 1.3900845237714473e-06f  // 0.9^128 (double-derived)
#define EPS 1e-8f
#define RADIUS 0.5f

typedef __attribute__((ext_vector_type(8))) short short8;   // bf16x8 MFMA frag
typedef __attribute__((ext_vector_type(4))) float f32x4;

static __device__ __forceinline__ unsigned short f2bf(float f) {
    unsigned u = __float_as_uint(f);
    u += 0x7FFFu + ((u >> 16) & 1u);          // RNE
    return (unsigned short)(u >> 16);
}
static __device__ __forceinline__ float bf2f(unsigned short h) {
    return __uint_as_float(((unsigned)h) << 16);
}

// ---------------- spectral norm scale (2 blocks: k and v) ----------------
__global__ __launch_bounds__(1024)
void spectral_kernel(const float* __restrict__ Wk,
                     const float* __restrict__ Wv,
                     const float* __restrict__ uk,
                     const float* __restrict__ uv,
                     float* __restrict__ scale_out) {
    const float* W  = (blockIdx.x == 0) ? Wk : Wv;
    const float* u0 = (blockIdx.x == 0) ? uk : uv;
    int tid = threadIdx.x;       // 0..1023 = d
    int lane = tid & 63;
    int wid = tid >> 6;          // 0..15
    __shared__ float u_s[N_DIM];
    __shared__ float v_s[D_DIM];
    __shared__ float t_s[N_DIM];
    __shared__ float red[16];
    __shared__ float bcs;
    if (tid < N_DIM) u_s[tid] = u0[tid];
    __syncthreads();
    for (int iter = 0; iter < 3; ++iter) {
        float acc = 0.f;
        #pragma unroll
        for (int nn = 0; nn < N_DIM; ++nn)
            acc += W[nn * D_DIM + tid] * u_s[nn];
        float ss = acc * acc;
        #pragma unroll
        for (int o = 32; o > 0; o >>= 1) ss += __shfl_xor(ss, o, 64);
        if (lane == 0) red[wid] = ss;
        __syncthreads();
        if (tid == 0) {
            float tot = 0.f;
            #pragma unroll
            for (int w2 = 0; w2 < 16; ++w2) tot += red[w2];
            bcs = 1.0f / (sqrtf(tot) + EPS);
        }
        __syncthreads();
        v_s[tid] = acc * bcs;
        __syncthreads();
        #pragma unroll
        for (int rr = 0; rr < 4; ++rr) {
            int r = wid * 4 + rr;
            float a = 0.f;
            #pragma unroll
            for (int e = 0; e < 16; ++e)
                a += W[r * D_DIM + lane + 64 * e] * v_s[lane + 64 * e];
            #pragma unroll
            for (int o = 32; o > 0; o >>= 1) a += __shfl_xor(a, o, 64);
            if (lane == 0) t_s[r] = a;
        }
        __syncthreads();
        if (wid == 0) {
            float uu = t_s[lane];
            float s2 = uu * uu;
            #pragma unroll
            for (int o = 32; o > 0; o >>= 1) s2 += __shfl_xor(s2, o, 64);
            float inv = 1.0f / (sqrtf(__shfl(s2, 0, 64)) + EPS);
            u_s[lane] = uu * inv;
        }
        __syncthreads();
    }
    if (wid == 0) {
        float val = t_s[lane] * u_s[lane];
        #pragma unroll
        for (int o = 32; o > 0; o >>= 1) val += __shfl_xor(val, o, 64);
        if (lane == 0) scale_out[blockIdx.x] = RADIUS / (fabsf(val) + EPS);
    }
}

// ------- build bf16 hi/lo of fused scaled W in MFMA-FRAGMENT-MAJOR order -------
// BP[g][s][kk][lane][e]: g = col-group (16 cols), s = K-step (64), kk = 32-k half,
// lane = flh*16 + fl15 (fl15 = col within group, flh = 8-k slice), e = k within 8.
// proj then loads each B fragment as one fully-coalesced 16B/lane read.
__global__ __launch_bounds__(256)
void build_wt_kernel(const float* __restrict__ Wk,
                     const float* __restrict__ Wv,
                     const float* __restrict__ Wq,
                     const float* __restrict__ scale,
                     unsigned short* __restrict__ BPh,
                     unsigned short* __restrict__ BPl) {
    int c = blockIdx.x;           // 0..191 (output col)
    int tid = threadIdx.x;        // 0..255, 4 k-values each
    const float* src;
    float sc;
    if (c < 64)       { src = Wk + (size_t)c * D_DIM;         sc = scale[0]; }
    else if (c < 128) { src = Wv + (size_t)(c - 64) * D_DIM;  sc = scale[1]; }
    else              { src = Wq + (size_t)(c - 128) * D_DIM; sc = 1.0f; }
    int g = c >> 4;
    int fl = c & 15;
    float4 w = *(const float4*)(src + tid * 4);
    float vals[4] = {w.x * sc, w.y * sc, w.z * sc, w.w * sc};
    #pragma unroll
    for (int e4 = 0; e4 < 4; ++e4) {
        int k = tid * 4 + e4;
        unsigned short h = f2bf(vals[e4]);
        unsigned short l = f2bf(vals[e4] - bf2f(h));
        int s  = k >> 6;
        int kk = (k >> 5) & 1;
        int flh = (k >> 3) & 3;
        int e  = k & 7;
        size_t idx = (size_t)g * 16384 + s * 1024 + kk * 512 + (flh * 16 + fl) * 8 + e;
        BPh[idx] = h;
        BPl[idx] = l;
    }
}

// ------------- projections via split-bf16 MFMA: kvq = x . Wt^T -------------
// R3 geometry: PBM=32, 512 blocks, 4 waves (wave wv -> cols [wv*48,+48), 2 M-tiles).
// A staged fp32->LDS as XOR-swizzled bf16 hi/lo (convert once), 2-deep prefetch.
// B frags from fragment-major pack: fully coalesced 16B/lane L2 loads.
#define PBM 32
#define PBK 64
__global__ __launch_bounds__(256)
void proj_mfma_kernel(const float* __restrict__ x,
                      const unsigned short* __restrict__ BPh,
                      const unsigned short* __restrict__ BPl,
                      float* __restrict__ kvq) {
    __shared__ __align__(16) unsigned short lds[2][2][PBM * PBK];  // 16 KB
    int tid = threadIdx.x;
    int lane = tid & 63;
    int wv = tid >> 6;                 // 0..3 -> cols [wv*48, +48)
    int fl15 = lane & 15;
    int flh = lane >> 4;               // 0..3
    int rowBase = blockIdx.x * PBM;

    // staging: thread t handles row t>>3, 8 floats at col (t&7)*8
    int r_st = tid >> 3;
    const float* xrow = x + (size_t)(rowBase + r_st) * D_DIM + (tid & 7) * 8;
    int wr_off = (r_st * 128 + (tid & 7) * 16) ^ ((r_st & 7) << 4);  // bytes

    // B pack base (lane-resolved)
    const unsigned short* bbh = BPh + (size_t)(wv * 3) * 16384 + lane * 8;
    const unsigned short* bbl = BPl + (size_t)(wv * 3) * 16384 + lane * 8;

    f32x4 acc[2][3];
    #pragma unroll
    for (int mt = 0; mt < 2; ++mt)
        #pragma unroll
        for (int nt = 0; nt < 3; ++nt) acc[mt][nt] = (f32x4)(0.f);

    // prologue: tile 0 -> LDS buf0; tile 1 -> regs
    float4 A0 = *(const float4*)(xrow);
    float4 A1 = *(const float4*)(xrow + 4);
    {
        float v[8] = {A0.x, A0.y, A0.z, A0.w, A1.x, A1.y, A1.z, A1.w};
        short8 hv, lv;
        #pragma unroll
        for (int e = 0; e < 8; ++e) {
            unsigned short hh = f2bf(v[e]);
            hv[e] = (short)hh;
            lv[e] = (short)f2bf(v[e] - bf2f(hh));
        }
        *(short8*)((char*)&lds[0][0][0] + wr_off) = hv;
        *(short8*)((char*)&lds[0][1][0] + wr_off) = lv;
    }
    float4 B0 = *(const float4*)(xrow + PBK);
    float4 B1 = *(const float4*)(xrow + PBK + 4);
    __syncthreads();

    for (int s = 0; s < 16; ++s) {
        // issue 2-ahead x load
        if (s < 14) {
            A0 = *(const float4*)(xrow + (s + 2) * PBK);
            A1 = *(const float4*)(xrow + (s + 2) * PBK + 4);
        }
        // B fragments: 12 coalesced 16B loads from the pack
        short8 bh[2][3], bl[2][3];
        #pragma unroll
        for (int nt = 0; nt < 3; ++nt)
            #pragma unroll
            for (int kk = 0; kk < 2; ++kk) {
                size_t off = (size_t)nt * 16384 + s * 1024 + kk * 512;
                bh[kk][nt] = *(const short8*)(bbh + off);
                bl[kk][nt] = *(const short8*)(bbl + off);
            }
        const char* ldsH = (const char*)&lds[s & 1][0][0];
        const char* ldsL = (const char*)&lds[s & 1][1][0];
        #pragma unroll
        for (int kk = 0; kk < 2; ++kk) {
            short8 ah[2], al[2];
            #pragma unroll
            for (int mt = 0; mt < 2; ++mt) {
                int row = mt * 16 + fl15;
                int off = (row * 128 + kk * 64 + flh * 16) ^ ((row & 7) << 4);
                ah[mt] = *(const short8*)(ldsH + off);
                al[mt] = *(const short8*)(ldsL + off);
            }
            #pragma unroll
            for (int mt = 0; mt < 2; ++mt)
                #pragma unroll
                for (int nt = 0; nt < 3; ++nt) {
                    acc[mt][nt] = __builtin_amdgcn_mfma_f32_16x16x32_bf16(
                        ah[mt], bh[kk][nt], acc[mt][nt], 0, 0, 0);
                    acc[mt][nt] = __builtin_amdgcn_mfma_f32_16x16x32_bf16(
                        ah[mt], bl[kk][nt], acc[mt][nt], 0, 0, 0);
                    acc[mt][nt] = __builtin_amdgcn_mfma_f32_16x16x32_bf16(
                        al[mt], bh[kk][nt], acc[mt][nt], 0, 0, 0);
                }
        }
        // write tile s+1 from regs into the other buffer
        if (s < 15) {
            float v[8] = {B0.x, B0.y, B0.z, B0.w, B1.x, B1.y, B1.z, B1.w};
            short8 hv, lv;
            #pragma unroll
            for (int e = 0; e < 8; ++e) {
                unsigned short hh = f2bf(v[e]);
                hv[e] = (short)hh;
                lv[e] = (short)f2bf(v[e] - bf2f(hh));
            }
            *(short8*)((char*)&lds[(s + 1) & 1][0][0] + wr_off) = hv;
            *(short8*)((char*)&lds[(s + 1) & 1][1][0] + wr_off) = lv;
        }
        B0 = A0; B1 = A1;
        __syncthreads();
    }

    // epilogue: C/D layout col=lane&15, row=(lane>>4)*4+reg  [m89]
    #pragma unroll
    for (int mt = 0; mt < 2; ++mt)
        #pragma unroll
        for (int nt = 0; nt < 3; ++nt) {
            int col = wv * 48 + nt * 16 + fl15;
            #pragma unroll
            for (int r = 0; r < 4; ++r) {
                int row = rowBase + mt * 16 + flh * 4 + r;
                kvq[(size_t)row * 192 + col] = acc[mt][nt][r];
            }
        }
}

// ------------- pass 1: chunk-local final states (zero-init) -------------
__global__ void pass1_kernel(const float* __restrict__ kvq,
                             float* __restrict__ local) {
    int w = (blockIdx.x * blockDim.x + threadIdx.x) >> 6;  // wave id: c*512 + b*64 + i
    int j = threadIdx.x & 63;
    int c = w >> 9;
    int rem = w & 511;
    int b = rem >> 6;
    int i = rem & 63;
    float s = 0.f;
    int t0 = c * CHUNK_LEN;
    for (int t = t0; t < t0 + CHUNK_LEN; ++t) {
        const float* base = kvq + (size_t)(t * B_DIM + b) * 192;
        float k = base[j];
        float v = base[64 + i];
        s = DECAY * s + v * k;
    }
    local[(size_t)w * 64 + j] = s;
}

// ------------- pass 2: fold own carry from `local`, write S0 row, S_all, output -------------
#define P2_WAVES 4
__global__ __launch_bounds__(256)
void pass2_kernel(const float* __restrict__ kvq,
                  const float* __restrict__ local,
                  const float* __restrict__ S0,
                  float* __restrict__ out,      // [T,B,n]
                  float* __restrict__ S_all) {  // [T+1,B,n,n]
    __shared__ __align__(16) float P[P2_WAVES][16][68];   // padded: conflict-free reads
    int widL = threadIdx.x >> 6;                 // wave in block
    int j = threadIdx.x & 63;
    int w = blockIdx.x * P2_WAVES + widL;        // global wave id: c*512 + b*64 + i
    int c = w >> 9;
    int rem = w & 511;
    int b = rem >> 6;
    int i = rem & 63;
    int tl = j & 15;          // t-slot this lane reduces
    int part = j >> 4;        // 16-column slice this lane sums

    // S0 row (replaces the memcpy node)
    if (c == 0)
        S_all[(size_t)b * 4096 + (size_t)i * 64 + j] = S0[((size_t)b * 64 + i) * 64 + j];

    // carry fold (replaces chunkscan kernel): uniform per wave
    float s = 0.f;
    for (int cp = 0; cp < c; ++cp)
        s = __builtin_fmaf(DECAY_L, s, local[((size_t)cp * 512 + b * 64 + i) * 64 + j]);

    int t0 = c * CHUNK_LEN;
    for (int tb = 0; tb < CHUNK_LEN; tb += 16) {
        #pragma unroll
        for (int u = 0; u < 16; ++u) {
            int t = t0 + tb + u;
            const float* base = kvq + (size_t)(t * B_DIM + b) * 192;
            float k = base[j];
            float v = base[64 + i];
            float q = base[128 + j];
            s = __builtin_fmaf(DECAY, s, v * k);
            S_all[((size_t)(t + 1) * B_DIM + b) * 4096 + (size_t)i * 64 + j] = s;
            P[widL][u][j] = s * q;
        }
        float acc = 0.f;
        #pragma unroll
        for (int rd = 0; rd < 4; ++rd) {
            const float4 a = *(const float4*)&P[widL][tl][part * 16 + rd * 4];
            acc += (a.x + a.y) + (a.z + a.w);
        }
        acc += __shfl_xor(acc, 16, 64);
        acc += __shfl_xor(acc, 32, 64);
        if (part == 0) {
            int t = t0 + tb + tl;
            float sg = 1.0f / (1.0f + __expf(-acc));
            out[(t * B_DIM + b) * 64 + i] = acc * acc * sg;
        }
    }
}

extern "C" void kernel_launch(void* const* d_in, const int* in_sizes, int n_in,
                              void* d_out, int out_size, void* d_ws, size_t ws_size,
                              hipStream_t stream) {
    const float* x  = (const float*)d_in[0];
    const float* S0 = (const float*)d_in[1];
    const float* Wk = (const float*)d_in[2];
    const float* Wv = (const float*)d_in[3];
    const float* Wq = (const float*)d_in[4];
    const float* uk = (const float*)d_in[5];
    const float* uv = (const float*)d_in[6];

    float* out   = (float*)d_out;                              // [T,B,n]
    float* S_all = out + (size_t)T_DIM * B_DIM * N_DIM;        // [T+1,B,n,n]

    float* ws    = (float*)d_ws;
    float* scale = ws;                                   // 2 floats (pad 64)
    float* kvq   = ws + 64;                              // 16384*192
    unsigned short* BPh = (unsigned short*)(kvq + (size_t)16384 * 192);  // 192*1024
    unsigned short* BPl = BPh + (size_t)192 * D_DIM;
    float* local = (float*)(BPl + (size_t)192 * D_DIM);  // 16*32768

    spectral_kernel<<<2, 1024, 0, stream>>>(Wk, Wv, uk, uv, scale);
    build_wt_kernel<<<192, 256, 0, stream>>>(Wk, Wv, Wq, scale, BPh, BPl);
    proj_mfma_kernel<<<T_DIM * B_DIM / PBM, 256, 0, stream>>>(x, BPh, BPl, kvq);
    pass1_kernel<<<NCHUNK * B_DIM * N_DIM / 4, 256, 0, stream>>>(kvq, local);
    pass2_kernel<<<NCHUNK * B_DIM * N_DIM / 4, 256, 0, stream>>>(kvq, local, S0, out, S_all);
}

// Round 7
// 155.605 us; speedup vs baseline: 1.5584x; 1.2190x over previous
//
#include <hip/hip_runtime.h>
#include <math.h>

#define T_DIM 2048
#define B_DIM 8
#define D_DIM 1024
#define N_DIM 64
#define NCHUNK 16
#define CHUNK_LEN 128              // T_DIM / NCHUNK
#define WARMUP 96                  // decay^97 ~ 3.6e-5: truncation error << threshold
#define DECAY 0.9f
#define EPS 1e-8f
#define RADIUS 0.5f

typedef __attribute__((ext_vector_type(8))) short short8;   // bf16x8 MFMA frag
typedef __attribute__((ext_vector_type(4))) float f32x4;

static __device__ __forceinline__ unsigned short f2bf(float f) {
    unsigned u = __float_as_uint(f);
    u += 0x7FFFu + ((u >> 16) & 1u);          // RNE
    return (unsigned short)(u >> 16);
}
static __device__ __forceinline__ float bf2f(unsigned short h) {
    return __uint_as_float(((unsigned)h) << 16);
}

// ---------------- spectral norm scale (2 blocks: k and v) ----------------
__global__ __launch_bounds__(1024)
void spectral_kernel(const float* __restrict__ Wk,
                     const float* __restrict__ Wv,
                     const float* __restrict__ uk,
                     const float* __restrict__ uv,
                     float* __restrict__ scale_out) {
    const float* W  = (blockIdx.x == 0) ? Wk : Wv;
    const float* u0 = (blockIdx.x == 0) ? uk : uv;
    int tid = threadIdx.x;       // 0..1023 = d
    int lane = tid & 63;
    int wid = tid >> 6;          // 0..15
    __shared__ float u_s[N_DIM];
    __shared__ float v_s[D_DIM];
    __shared__ float t_s[N_DIM];
    __shared__ float red[16];
    __shared__ float bcs;
    if (tid < N_DIM) u_s[tid] = u0[tid];
    __syncthreads();
    for (int iter = 0; iter < 3; ++iter) {
        float acc = 0.f;
        #pragma unroll
        for (int nn = 0; nn < N_DIM; ++nn)
            acc += W[nn * D_DIM + tid] * u_s[nn];
        float ss = acc * acc;
        #pragma unroll
        for (int o = 32; o > 0; o >>= 1) ss += __shfl_xor(ss, o, 64);
        if (lane == 0) red[wid] = ss;
        __syncthreads();
        if (tid == 0) {
            float tot = 0.f;
            #pragma unroll
            for (int w2 = 0; w2 < 16; ++w2) tot += red[w2];
            bcs = 1.0f / (sqrtf(tot) + EPS);
        }
        __syncthreads();
        v_s[tid] = acc * bcs;
        __syncthreads();
        #pragma unroll
        for (int rr = 0; rr < 4; ++rr) {
            int r = wid * 4 + rr;
            float a = 0.f;
            #pragma unroll
            for (int e = 0; e < 16; ++e)
                a += W[r * D_DIM + lane + 64 * e] * v_s[lane + 64 * e];
            #pragma unroll
            for (int o = 32; o > 0; o >>= 1) a += __shfl_xor(a, o, 64);
            if (lane == 0) t_s[r] = a;
        }
        __syncthreads();
        if (wid == 0) {
            float uu = t_s[lane];
            float s2 = uu * uu;
            #pragma unroll
            for (int o = 32; o > 0; o >>= 1) s2 += __shfl_xor(s2, o, 64);
            float inv = 1.0f / (sqrtf(__shfl(s2, 0, 64)) + EPS);
            u_s[lane] = uu * inv;
        }
        __syncthreads();
    }
    if (wid == 0) {
        float val = t_s[lane] * u_s[lane];
        #pragma unroll
        for (int o = 32; o > 0; o >>= 1) val += __shfl_xor(val, o, 64);
        if (lane == 0) scale_out[blockIdx.x] = RADIUS / (fabsf(val) + EPS);
    }
}

// ------- build bf16 hi/lo of fused scaled W in MFMA-FRAGMENT-MAJOR order -------
// BP[g][sg][kk][lane][e]: g = col-group (16 cols), sg = 32-wide K-step (0..31),
// kk = 32-k half of the 64-k unit... layout identical to R6 (proven absmax 1.0):
// idx = g*16384 + s64*1024 + kk*512 + (flh*16 + fl)*8 + e, s64 = k>>6.
__global__ __launch_bounds__(256)
void build_wt_kernel(const float* __restrict__ Wk,
                     const float* __restrict__ Wv,
                     const float* __restrict__ Wq,
                     const float* __restrict__ scale,
                     unsigned short* __restrict__ BPh,
                     unsigned short* __restrict__ BPl) {
    int c = blockIdx.x;           // 0..191 (output col)
    int tid = threadIdx.x;        // 0..255, 4 k-values each
    const float* src;
    float sc;
    if (c < 64)       { src = Wk + (size_t)c * D_DIM;         sc = scale[0]; }
    else if (c < 128) { src = Wv + (size_t)(c - 64) * D_DIM;  sc = scale[1]; }
    else              { src = Wq + (size_t)(c - 128) * D_DIM; sc = 1.0f; }
    int g = c >> 4;
    int fl = c & 15;
    float4 w = *(const float4*)(src + tid * 4);
    float vals[4] = {w.x * sc, w.y * sc, w.z * sc, w.w * sc};
    #pragma unroll
    for (int e4 = 0; e4 < 4; ++e4) {
        int k = tid * 4 + e4;
        unsigned short h = f2bf(vals[e4]);
        unsigned short l = f2bf(vals[e4] - bf2f(h));
        int s  = k >> 6;
        int kk = (k >> 5) & 1;
        int flh = (k >> 3) & 3;
        int e  = k & 7;
        size_t idx = (size_t)g * 16384 + s * 1024 + kk * 512 + (flh * 16 + fl) * 8 + e;
        BPh[idx] = h;
        BPl[idx] = l;
    }
}

// ------------- projections via split-bf16 MFMA: kvq = x . Wt^T -------------
// PBM=32 rows, 512 blocks, 4 waves (wave wv -> cols [wv*48,+48), 2 M-tiles).
// K staged in 8 x 128-k chunks, double-buffered 32 KB LDS, ONE barrier/stage.
// Next-stage x loads issued BEFORE the 72-MFMA block (barrier-free region).
#define PBM 32
#define KSTAGE 128
__global__ __launch_bounds__(256)
void proj_mfma_kernel(const float* __restrict__ x,
                      const unsigned short* __restrict__ BPh,
                      const unsigned short* __restrict__ BPl,
                      float* __restrict__ kvq) {
    __shared__ __align__(16) unsigned short ldsA[2][2][PBM * KSTAGE];  // 32 KB
    int tid = threadIdx.x;
    int lane = tid & 63;
    int wv = tid >> 6;                 // 0..3 -> cols [wv*48, +48)
    int fl15 = lane & 15;
    int flh = lane >> 4;               // 0..3
    int rowBase = blockIdx.x * PBM;

    // staging: thread t -> row t>>3, 8 floats at k = (t&7)*8 + it*64 (it=0,1)
    int r_st = tid >> 3;
    int sub  = tid & 7;
    const float* xrow = x + (size_t)(rowBase + r_st) * D_DIM + sub * 8;
    // LDS write byte (plane-relative): row*256 + it*128 + (sub*16 ^ ((row&7)<<4))
    int wb0 = r_st * 256 + ((sub * 16) ^ ((r_st & 7) << 4));
    int wb1 = wb0 + 128;

    // B pack base (lane-resolved)
    const unsigned short* bbh = BPh + (size_t)(wv * 3) * 16384 + lane * 8;
    const unsigned short* bbl = BPl + (size_t)(wv * 3) * 16384 + lane * 8;

    f32x4 acc[2][3];
    #pragma unroll
    for (int mt = 0; mt < 2; ++mt)
        #pragma unroll
        for (int nt = 0; nt < 3; ++nt) acc[mt][nt] = (f32x4)(0.f);

    // prologue: stage qt=0 into buf0
    {
        float4 a0 = *(const float4*)(xrow);
        float4 a1 = *(const float4*)(xrow + 4);
        float4 b0 = *(const float4*)(xrow + 64);
        float4 b1 = *(const float4*)(xrow + 68);
        float v0[8] = {a0.x, a0.y, a0.z, a0.w, a1.x, a1.y, a1.z, a1.w};
        float v1[8] = {b0.x, b0.y, b0.z, b0.w, b1.x, b1.y, b1.z, b1.w};
        short8 h0, l0, h1, l1;
        #pragma unroll
        for (int e = 0; e < 8; ++e) {
            unsigned short hh = f2bf(v0[e]);
            h0[e] = (short)hh; l0[e] = (short)f2bf(v0[e] - bf2f(hh));
            hh = f2bf(v1[e]);
            h1[e] = (short)hh; l1[e] = (short)f2bf(v1[e] - bf2f(hh));
        }
        char* pH = (char*)&ldsA[0][0][0];
        char* pL = (char*)&ldsA[0][1][0];
        *(short8*)(pH + wb0) = h0; *(short8*)(pL + wb0) = l0;
        *(short8*)(pH + wb1) = h1; *(short8*)(pL + wb1) = l1;
    }
    __syncthreads();

    #pragma unroll 1
    for (int qt = 0; qt < 8; ++qt) {
        int buf = qt & 1;
        // issue next-stage x loads FIRST (covered by the MFMA block below)
        float4 n0a, n0b, n1a, n1b;
        if (qt < 7) {
            const float* nx = xrow + (qt + 1) * KSTAGE;
            n0a = *(const float4*)(nx);
            n0b = *(const float4*)(nx + 4);
            n1a = *(const float4*)(nx + 64);
            n1b = *(const float4*)(nx + 68);
        }
        const char* pH = (const char*)&ldsA[buf][0][0];
        const char* pL = (const char*)&ldsA[buf][1][0];
        #pragma unroll
        for (int s = 0; s < 2; ++s) {
            int sg = qt * 2 + s;
            short8 bh[2][3], bl[2][3];
            #pragma unroll
            for (int nt = 0; nt < 3; ++nt)
                #pragma unroll
                for (int kk = 0; kk < 2; ++kk) {
                    size_t off = (size_t)nt * 16384 + sg * 1024 + kk * 512;
                    bh[kk][nt] = *(const short8*)(bbh + off);
                    bl[kk][nt] = *(const short8*)(bbl + off);
                }
            #pragma unroll
            for (int kk = 0; kk < 2; ++kk) {
                short8 ah[2], al[2];
                #pragma unroll
                for (int mt = 0; mt < 2; ++mt) {
                    int row = mt * 16 + fl15;
                    int off = row * 256 + s * 128 +
                              ((kk * 64 + flh * 16) ^ ((row & 7) << 4));
                    ah[mt] = *(const short8*)(pH + off);
                    al[mt] = *(const short8*)(pL + off);
                }
                #pragma unroll
                for (int mt = 0; mt < 2; ++mt)
                    #pragma unroll
                    for (int nt = 0; nt < 3; ++nt) {
                        acc[mt][nt] = __builtin_amdgcn_mfma_f32_16x16x32_bf16(
                            ah[mt], bh[kk][nt], acc[mt][nt], 0, 0, 0);
                        acc[mt][nt] = __builtin_amdgcn_mfma_f32_16x16x32_bf16(
                            ah[mt], bl[kk][nt], acc[mt][nt], 0, 0, 0);
                        acc[mt][nt] = __builtin_amdgcn_mfma_f32_16x16x32_bf16(
                            al[mt], bh[kk][nt], acc[mt][nt], 0, 0, 0);
                    }
            }
        }
        // convert + write next stage into the other buffer, then one barrier
        if (qt < 7) {
            float v0[8] = {n0a.x, n0a.y, n0a.z, n0a.w, n0b.x, n0b.y, n0b.z, n0b.w};
            float v1[8] = {n1a.x, n1a.y, n1a.z, n1a.w, n1b.x, n1b.y, n1b.z, n1b.w};
            short8 h0, l0, h1, l1;
            #pragma unroll
            for (int e = 0; e < 8; ++e) {
                unsigned short hh = f2bf(v0[e]);
                h0[e] = (short)hh; l0[e] = (short)f2bf(v0[e] - bf2f(hh));
                hh = f2bf(v1[e]);
                h1[e] = (short)hh; l1[e] = (short)f2bf(v1[e] - bf2f(hh));
            }
            char* qH = (char*)&ldsA[buf ^ 1][0][0];
            char* qL = (char*)&ldsA[buf ^ 1][1][0];
            *(short8*)(qH + wb0) = h0; *(short8*)(qL + wb0) = l0;
            *(short8*)(qH + wb1) = h1; *(short8*)(qL + wb1) = l1;
        }
        __syncthreads();
    }

    // epilogue: C/D layout col=lane&15, row=(lane>>4)*4+reg  [m89]
    #pragma unroll
    for (int mt = 0; mt < 2; ++mt)
        #pragma unroll
        for (int nt = 0; nt < 3; ++nt) {
            int col = wv * 48 + nt * 16 + fl15;
            #pragma unroll
            for (int r = 0; r < 4; ++r) {
                int row = rowBase + mt * 16 + flh * 4 + r;
                kvq[(size_t)row * 192 + col] = acc[mt][nt][r];
            }
        }
}

// ------------- fused scan: warm-up over prev chunk's tail replaces pass1+carry -------------
// wave = (c,b,i); 96-step warm-up (c>0) then 128-step store-scan with silu output.
#define P2_WAVES 4
__global__ __launch_bounds__(256)
void scan_kernel(const float* __restrict__ kvq,
                 const float* __restrict__ S0,
                 float* __restrict__ out,      // [T,B,n]
                 float* __restrict__ S_all) {  // [T+1,B,n,n]
    __shared__ __align__(16) float P[P2_WAVES][16][68];   // padded: conflict-free reads
    int widL = threadIdx.x >> 6;                 // wave in block
    int j = threadIdx.x & 63;
    int w = blockIdx.x * P2_WAVES + widL;        // global wave id: c*512 + b*64 + i
    int c = w >> 9;
    int rem = w & 511;
    int b = rem >> 6;
    int i = rem & 63;
    int tl = j & 15;          // t-slot this lane reduces
    int part = j >> 4;        // 16-column slice this lane sums

    // S0 row (c==0 blocks cover all (b,i))
    if (c == 0)
        S_all[(size_t)b * 4096 + (size_t)i * 64 + j] = S0[((size_t)b * 64 + i) * 64 + j];

    float s = 0.f;
    int t0 = c * CHUNK_LEN;
    if (c > 0) {
        #pragma unroll 4
        for (int t = t0 - WARMUP; t < t0; ++t) {
            const float* base = kvq + (size_t)(t * B_DIM + b) * 192;
            s = __builtin_fmaf(DECAY, s, base[64 + i] * base[j]);
        }
    }

    for (int tb = 0; tb < CHUNK_LEN; tb += 16) {
        #pragma unroll
        for (int u = 0; u < 16; ++u) {
            int t = t0 + tb + u;
            const float* base = kvq + (size_t)(t * B_DIM + b) * 192;
            float k = base[j];
            float v = base[64 + i];
            float q = base[128 + j];
            s = __builtin_fmaf(DECAY, s, v * k);
            S_all[((size_t)(t + 1) * B_DIM + b) * 4096 + (size_t)i * 64 + j] = s;
            P[widL][u][j] = s * q;
        }
        float acc = 0.f;
        #pragma unroll
        for (int rd = 0; rd < 4; ++rd) {
            const float4 a = *(const float4*)&P[widL][tl][part * 16 + rd * 4];
            acc += (a.x + a.y) + (a.z + a.w);
        }
        acc += __shfl_xor(acc, 16, 64);
        acc += __shfl_xor(acc, 32, 64);
        if (part == 0) {
            int t = t0 + tb + tl;
            float sg = 1.0f / (1.0f + __expf(-acc));
            out[(t * B_DIM + b) * 64 + i] = acc * acc * sg;
        }
    }
}

extern "C" void kernel_launch(void* const* d_in, const int* in_sizes, int n_in,
                              void* d_out, int out_size, void* d_ws, size_t ws_size,
                              hipStream_t stream) {
    const float* x  = (const float*)d_in[0];
    const float* S0 = (const float*)d_in[1];
    const float* Wk = (const float*)d_in[2];
    const float* Wv = (const float*)d_in[3];
    const float* Wq = (const float*)d_in[4];
    const float* uk = (const float*)d_in[5];
    const float* uv = (const float*)d_in[6];

    float* out   = (float*)d_out;                              // [T,B,n]
    float* S_all = out + (size_t)T_DIM * B_DIM * N_DIM;        // [T+1,B,n,n]

    float* ws    = (float*)d_ws;
    float* scale = ws;                                   // 2 floats (pad 64)
    float* kvq   = ws + 64;                              // 16384*192
    unsigned short* BPh = (unsigned short*)(kvq + (size_t)16384 * 192);  // 192*1024
    unsigned short* BPl = BPh + (size_t)192 * D_DIM;

    spectral_kernel<<<2, 1024, 0, stream>>>(Wk, Wv, uk, uv, scale);
    build_wt_kernel<<<192, 256, 0, stream>>>(Wk, Wv, Wq, scale, BPh, BPl);
    proj_mfma_kernel<<<T_DIM * B_DIM / PBM, 256, 0, stream>>>(x, BPh, BPl, kvq);
    scan_kernel<<<NCHUNK * B_DIM * N_DIM / 4, 256, 0, stream>>>(kvq, S0, out, S_all);
}

// Round 8
// 142.921 us; speedup vs baseline: 1.6967x; 1.0887x over previous
//
#include <hip/hip_runtime.h>
#include <math.h>

#define T_DIM 2048
#define B_DIM 8
#define D_DIM 1024
#define N_DIM 64
#define NCHUNK 16
#define CHUNK_LEN 128              // T_DIM / NCHUNK
#define DECAY 0.9f
#define EPS 1e-8f
#define RADIUS 0.5f

typedef __attribute__((ext_vector_type(8))) short short8;   // bf16x8 MFMA frag
typedef __attribute__((ext_vector_type(4))) float f32x4;

static __device__ __forceinline__ unsigned short f2bf(float f) {
    unsigned u = __float_as_uint(f);
    u += 0x7FFFu + ((u >> 16) & 1u);          // RNE
    return (unsigned short)(u >> 16);
}
static __device__ __forceinline__ float bf2f(unsigned short h) {
    return __uint_as_float(((unsigned)h) << 16);
}

// ---------------- spectral norm scale (2 blocks: k and v) ----------------
__global__ __launch_bounds__(1024)
void spectral_kernel(const float* __restrict__ Wk,
                     const float* __restrict__ Wv,
                     const float* __restrict__ uk,
                     const float* __restrict__ uv,
                     float* __restrict__ scale_out) {
    const float* W  = (blockIdx.x == 0) ? Wk : Wv;
    const float* u0 = (blockIdx.x == 0) ? uk : uv;
    int tid = threadIdx.x;       // 0..1023 = d
    int lane = tid & 63;
    int wid = tid >> 6;          // 0..15
    __shared__ float u_s[N_DIM];
    __shared__ float v_s[D_DIM];
    __shared__ float t_s[N_DIM];
    __shared__ float red[16];
    __shared__ float bcs;
    if (tid < N_DIM) u_s[tid] = u0[tid];
    __syncthreads();
    for (int iter = 0; iter < 3; ++iter) {
        float acc = 0.f;
        #pragma unroll
        for (int nn = 0; nn < N_DIM; ++nn)
            acc += W[nn * D_DIM + tid] * u_s[nn];
        float ss = acc * acc;
        #pragma unroll
        for (int o = 32; o > 0; o >>= 1) ss += __shfl_xor(ss, o, 64);
        if (lane == 0) red[wid] = ss;
        __syncthreads();
        if (tid == 0) {
            float tot = 0.f;
            #pragma unroll
            for (int w2 = 0; w2 < 16; ++w2) tot += red[w2];
            bcs = 1.0f / (sqrtf(tot) + EPS);
        }
        __syncthreads();
        v_s[tid] = acc * bcs;
        __syncthreads();
        #pragma unroll
        for (int rr = 0; rr < 4; ++rr) {
            int r = wid * 4 + rr;
            float a = 0.f;
            #pragma unroll
            for (int e = 0; e < 16; ++e)
                a += W[r * D_DIM + lane + 64 * e] * v_s[lane + 64 * e];
            #pragma unroll
            for (int o = 32; o > 0; o >>= 1) a += __shfl_xor(a, o, 64);
            if (lane == 0) t_s[r] = a;
        }
        __syncthreads();
        if (wid == 0) {
            float uu = t_s[lane];
            float s2 = uu * uu;
            #pragma unroll
            for (int o = 32; o > 0; o >>= 1) s2 += __shfl_xor(s2, o, 64);
            float inv = 1.0f / (sqrtf(__shfl(s2, 0, 64)) + EPS);
            u_s[lane] = uu * inv;
        }
        __syncthreads();
    }
    if (wid == 0) {
        float val = t_s[lane] * u_s[lane];
        #pragma unroll
        for (int o = 32; o > 0; o >>= 1) val += __shfl_xor(val, o, 64);
        if (lane == 0) scale_out[blockIdx.x] = RADIUS / (fabsf(val) + EPS);
    }
}

// ------- build bf16 hi/lo of fused scaled W in MFMA-FRAGMENT-MAJOR order -------
// idx = g*16384 + s64*1024 + kk*512 + (flh*16 + fl)*8 + e  (proven absmax 1.0)
__global__ __launch_bounds__(256)
void build_wt_kernel(const float* __restrict__ Wk,
                     const float* __restrict__ Wv,
                     const float* __restrict__ Wq,
                     const float* __restrict__ scale,
                     unsigned short* __restrict__ BPh,
                     unsigned short* __restrict__ BPl) {
    int c = blockIdx.x;           // 0..191 (output col)
    int tid = threadIdx.x;        // 0..255, 4 k-values each
    const float* src;
    float sc;
    if (c < 64)       { src = Wk + (size_t)c * D_DIM;         sc = scale[0]; }
    else if (c < 128) { src = Wv + (size_t)(c - 64) * D_DIM;  sc = scale[1]; }
    else              { src = Wq + (size_t)(c - 128) * D_DIM; sc = 1.0f; }
    int g = c >> 4;
    int fl = c & 15;
    float4 w = *(const float4*)(src + tid * 4);
    float vals[4] = {w.x * sc, w.y * sc, w.z * sc, w.w * sc};
    #pragma unroll
    for (int e4 = 0; e4 < 4; ++e4) {
        int k = tid * 4 + e4;
        unsigned short h = f2bf(vals[e4]);
        unsigned short l = f2bf(vals[e4] - bf2f(h));
        int s  = k >> 6;
        int kk = (k >> 5) & 1;
        int flh = (k >> 3) & 3;
        int e  = k & 7;
        size_t idx = (size_t)g * 16384 + s * 1024 + kk * 512 + (flh * 16 + fl) * 8 + e;
        BPh[idx] = h;
        BPl[idx] = l;
    }
}

// ------------- projections via split-bf16 MFMA (unchanged from R7) -------------
#define PBM 32
#define KSTAGE 128
__global__ __launch_bounds__(256)
void proj_mfma_kernel(const float* __restrict__ x,
                      const unsigned short* __restrict__ BPh,
                      const unsigned short* __restrict__ BPl,
                      float* __restrict__ kvq) {
    __shared__ __align__(16) unsigned short ldsA[2][2][PBM * KSTAGE];  // 32 KB
    int tid = threadIdx.x;
    int lane = tid & 63;
    int wv = tid >> 6;                 // 0..3 -> cols [wv*48, +48)
    int fl15 = lane & 15;
    int flh = lane >> 4;               // 0..3
    int rowBase = blockIdx.x * PBM;

    int r_st = tid >> 3;
    int sub  = tid & 7;
    const float* xrow = x + (size_t)(rowBase + r_st) * D_DIM + sub * 8;
    int wb0 = r_st * 256 + ((sub * 16) ^ ((r_st & 7) << 4));
    int wb1 = wb0 + 128;

    const unsigned short* bbh = BPh + (size_t)(wv * 3) * 16384 + lane * 8;
    const unsigned short* bbl = BPl + (size_t)(wv * 3) * 16384 + lane * 8;

    f32x4 acc[2][3];
    #pragma unroll
    for (int mt = 0; mt < 2; ++mt)
        #pragma unroll
        for (int nt = 0; nt < 3; ++nt) acc[mt][nt] = (f32x4)(0.f);

    {
        float4 a0 = *(const float4*)(xrow);
        float4 a1 = *(const float4*)(xrow + 4);
        float4 b0 = *(const float4*)(xrow + 64);
        float4 b1 = *(const float4*)(xrow + 68);
        float v0[8] = {a0.x, a0.y, a0.z, a0.w, a1.x, a1.y, a1.z, a1.w};
        float v1[8] = {b0.x, b0.y, b0.z, b0.w, b1.x, b1.y, b1.z, b1.w};
        short8 h0, l0, h1, l1;
        #pragma unroll
        for (int e = 0; e < 8; ++e) {
            unsigned short hh = f2bf(v0[e]);
            h0[e] = (short)hh; l0[e] = (short)f2bf(v0[e] - bf2f(hh));
            hh = f2bf(v1[e]);
            h1[e] = (short)hh; l1[e] = (short)f2bf(v1[e] - bf2f(hh));
        }
        char* pH = (char*)&ldsA[0][0][0];
        char* pL = (char*)&ldsA[0][1][0];
        *(short8*)(pH + wb0) = h0; *(short8*)(pL + wb0) = l0;
        *(short8*)(pH + wb1) = h1; *(short8*)(pL + wb1) = l1;
    }
    __syncthreads();

    #pragma unroll 1
    for (int qt = 0; qt < 8; ++qt) {
        int buf = qt & 1;
        float4 n0a, n0b, n1a, n1b;
        if (qt < 7) {
            const float* nx = xrow + (qt + 1) * KSTAGE;
            n0a = *(const float4*)(nx);
            n0b = *(const float4*)(nx + 4);
            n1a = *(const float4*)(nx + 64);
            n1b = *(const float4*)(nx + 68);
        }
        const char* pH = (const char*)&ldsA[buf][0][0];
        const char* pL = (const char*)&ldsA[buf][1][0];
        #pragma unroll
        for (int s = 0; s < 2; ++s) {
            int sg = qt * 2 + s;
            short8 bh[2][3], bl[2][3];
            #pragma unroll
            for (int nt = 0; nt < 3; ++nt)
                #pragma unroll
                for (int kk = 0; kk < 2; ++kk) {
                    size_t off = (size_t)nt * 16384 + sg * 1024 + kk * 512;
                    bh[kk][nt] = *(const short8*)(bbh + off);
                    bl[kk][nt] = *(const short8*)(bbl + off);
                }
            #pragma unroll
            for (int kk = 0; kk < 2; ++kk) {
                short8 ah[2], al[2];
                #pragma unroll
                for (int mt = 0; mt < 2; ++mt) {
                    int row = mt * 16 + fl15;
                    int off = row * 256 + s * 128 +
                              ((kk * 64 + flh * 16) ^ ((row & 7) << 4));
                    ah[mt] = *(const short8*)(pH + off);
                    al[mt] = *(const short8*)(pL + off);
                }
                #pragma unroll
                for (int mt = 0; mt < 2; ++mt)
                    #pragma unroll
                    for (int nt = 0; nt < 3; ++nt) {
                        acc[mt][nt] = __builtin_amdgcn_mfma_f32_16x16x32_bf16(
                            ah[mt], bh[kk][nt], acc[mt][nt], 0, 0, 0);
                        acc[mt][nt] = __builtin_amdgcn_mfma_f32_16x16x32_bf16(
                            ah[mt], bl[kk][nt], acc[mt][nt], 0, 0, 0);
                        acc[mt][nt] = __builtin_amdgcn_mfma_f32_16x16x32_bf16(
                            al[mt], bh[kk][nt], acc[mt][nt], 0, 0, 0);
                    }
            }
        }
        if (qt < 7) {
            float v0[8] = {n0a.x, n0a.y, n0a.z, n0a.w, n0b.x, n0b.y, n0b.z, n0b.w};
            float v1[8] = {n1a.x, n1a.y, n1a.z, n1a.w, n1b.x, n1b.y, n1b.z, n1b.w};
            short8 h0, l0, h1, l1;
            #pragma unroll
            for (int e = 0; e < 8; ++e) {
                unsigned short hh = f2bf(v0[e]);
                h0[e] = (short)hh; l0[e] = (short)f2bf(v0[e] - bf2f(hh));
                hh = f2bf(v1[e]);
                h1[e] = (short)hh; l1[e] = (short)f2bf(v1[e] - bf2f(hh));
            }
            char* qH = (char*)&ldsA[buf ^ 1][0][0];
            char* qL = (char*)&ldsA[buf ^ 1][1][0];
            *(short8*)(qH + wb0) = h0; *(short8*)(qL + wb0) = l0;
            *(short8*)(qH + wb1) = h1; *(short8*)(qL + wb1) = l1;
        }
        __syncthreads();
    }

    #pragma unroll
    for (int mt = 0; mt < 2; ++mt)
        #pragma unroll
        for (int nt = 0; nt < 3; ++nt) {
            int col = wv * 48 + nt * 16 + fl15;
            #pragma unroll
            for (int r = 0; r < 4; ++r) {
                int row = rowBase + mt * 16 + flh * 4 + r;
                kvq[(size_t)row * 192 + col] = acc[mt][nt][r];
            }
        }
}

// ------------- carry init: S_init[c] = scan of full previous chunk (window 128) -------------
// thread per (i, j4): 4 independent fma chains; 480 blocks = (c-1)*32 + b*4 + iq.
// s_final = sum_u decay^(127-u) p[tp+u] = S[t0-1] (window-truncated, err ~1.3e-6 rel)
__global__ __launch_bounds__(256)
void carry_init_kernel(const float* __restrict__ kvq,
                       float* __restrict__ S_init) {
    int blk = blockIdx.x;          // 0..479
    int c   = (blk >> 5) + 1;      // 1..15
    int rem = blk & 31;
    int b   = rem >> 2;
    int iq  = rem & 3;
    int i   = iq * 16 + (threadIdx.x >> 4);
    int j4  = (threadIdx.x & 15) * 4;
    int tp  = (c - 1) * CHUNK_LEN;
    float4 s4 = {0.f, 0.f, 0.f, 0.f};
    #pragma unroll 4
    for (int u = 0; u < CHUNK_LEN; ++u) {
        const float* base = kvq + (size_t)((tp + u) * B_DIM + b) * 192;
        float v = base[64 + i];
        float4 k4 = *(const float4*)(base + j4);
        s4.x = __builtin_fmaf(DECAY, s4.x, v * k4.x);
        s4.y = __builtin_fmaf(DECAY, s4.y, v * k4.y);
        s4.z = __builtin_fmaf(DECAY, s4.z, v * k4.z);
        s4.w = __builtin_fmaf(DECAY, s4.w, v * k4.w);
    }
    *(float4*)&S_init[(((size_t)c * B_DIM + b) * 64 + i) * 64 + j4] = s4;
}

// ------------- scan: init from S_init, 128 store-steps, NT stores for S_all -------------
#define P2_WAVES 4
__global__ __launch_bounds__(256)
void scan_kernel(const float* __restrict__ kvq,
                 const float* __restrict__ S_init,
                 const float* __restrict__ S0,
                 float* __restrict__ out,      // [T,B,n]
                 float* __restrict__ S_all) {  // [T+1,B,n,n]
    __shared__ __align__(16) float P[P2_WAVES][16][68];   // padded: conflict-free reads
    int widL = threadIdx.x >> 6;                 // wave in block
    int j = threadIdx.x & 63;
    int w = blockIdx.x * P2_WAVES + widL;        // global wave id: c*512 + b*64 + i
    int c = w >> 9;
    int rem = w & 511;
    int b = rem >> 6;
    int i = rem & 63;
    int tl = j & 15;          // t-slot this lane reduces
    int part = j >> 4;        // 16-column slice this lane sums

    // S0 row (c==0 blocks cover all (b,i))
    if (c == 0)
        S_all[(size_t)b * 4096 + (size_t)i * 64 + j] = S0[((size_t)b * 64 + i) * 64 + j];

    float s = 0.f;
    if (c > 0)
        s = S_init[(((size_t)c * B_DIM + b) * 64 + i) * 64 + j];

    int t0 = c * CHUNK_LEN;
    for (int tb = 0; tb < CHUNK_LEN; tb += 16) {
        #pragma unroll
        for (int u = 0; u < 16; ++u) {
            int t = t0 + tb + u;
            const float* base = kvq + (size_t)(t * B_DIM + b) * 192;
            float k = base[j];
            float v = base[64 + i];
            float q = base[128 + j];
            s = __builtin_fmaf(DECAY, s, v * k);
            __builtin_nontemporal_store(
                s, &S_all[((size_t)(t + 1) * B_DIM + b) * 4096 + (size_t)i * 64 + j]);
            P[widL][u][j] = s * q;
        }
        float acc = 0.f;
        #pragma unroll
        for (int rd = 0; rd < 4; ++rd) {
            const float4 a = *(const float4*)&P[widL][tl][part * 16 + rd * 4];
            acc += (a.x + a.y) + (a.z + a.w);
        }
        acc += __shfl_xor(acc, 16, 64);
        acc += __shfl_xor(acc, 32, 64);
        if (part == 0) {
            int t = t0 + tb + tl;
            float sg = 1.0f / (1.0f + __expf(-acc));
            out[(t * B_DIM + b) * 64 + i] = acc * acc * sg;
        }
    }
}

extern "C" void kernel_launch(void* const* d_in, const int* in_sizes, int n_in,
                              void* d_out, int out_size, void* d_ws, size_t ws_size,
                              hipStream_t stream) {
    const float* x  = (const float*)d_in[0];
    const float* S0 = (const float*)d_in[1];
    const float* Wk = (const float*)d_in[2];
    const float* Wv = (const float*)d_in[3];
    const float* Wq = (const float*)d_in[4];
    const float* uk = (const float*)d_in[5];
    const float* uv = (const float*)d_in[6];

    float* out   = (float*)d_out;                              // [T,B,n]
    float* S_all = out + (size_t)T_DIM * B_DIM * N_DIM;        // [T+1,B,n,n]

    float* ws    = (float*)d_ws;
    float* scale = ws;                                   // 2 floats (pad 64)
    float* kvq   = ws + 64;                              // 16384*192
    unsigned short* BPh = (unsigned short*)(kvq + (size_t)16384 * 192);  // 192*1024
    unsigned short* BPl = BPh + (size_t)192 * D_DIM;
    float* S_init = (float*)(BPl + (size_t)192 * D_DIM); // 16*8*64*64 = 524288 floats

    spectral_kernel<<<2, 1024, 0, stream>>>(Wk, Wv, uk, uv, scale);
    build_wt_kernel<<<192, 256, 0, stream>>>(Wk, Wv, Wq, scale, BPh, BPl);
    proj_mfma_kernel<<<T_DIM * B_DIM / PBM, 256, 0, stream>>>(x, BPh, BPl, kvq);
    carry_init_kernel<<<(NCHUNK - 1) * 32, 256, 0, stream>>>(kvq, S_init);
    scan_kernel<<<NCHUNK * B_DIM * N_DIM / 4, 256, 0, stream>>>(kvq, S_init, S0, out, S_all);
}

// Round 9
// 142.508 us; speedup vs baseline: 1.7016x; 1.0029x over previous
//
#include <hip/hip_runtime.h>
#include <math.h>

#define T_DIM 2048
#define B_DIM 8
#define D_DIM 1024
#define N_DIM 64
#define NCHUNK 16
#define CHUNK_LEN 128              // T_DIM / NCHUNK
#define DECAY 0.9f
#define EPS 1e-8f
#define RADIUS 0.5f

typedef __attribute__((ext_vector_type(8))) short short8;   // bf16x8 MFMA frag
typedef __attribute__((ext_vector_type(4))) float f32x4;

static __device__ __forceinline__ unsigned short f2bf(float f) {
    unsigned u = __float_as_uint(f);
    u += 0x7FFFu + ((u >> 16) & 1u);          // RNE
    return (unsigned short)(u >> 16);
}
static __device__ __forceinline__ float bf2f(unsigned short h) {
    return __uint_as_float(((unsigned)h) << 16);
}

// counted barrier: flush LDS writes, sync waves, do NOT drain vmcnt (T4)
static __device__ __forceinline__ void bar_lgkm() {
    asm volatile("s_waitcnt lgkmcnt(0)" ::: "memory");
    __builtin_amdgcn_s_barrier();
    asm volatile("" ::: "memory");
}

// ---------------- spectral norm scale (2 blocks: k and v) ----------------
__global__ __launch_bounds__(1024)
void spectral_kernel(const float* __restrict__ Wk,
                     const float* __restrict__ Wv,
                     const float* __restrict__ uk,
                     const float* __restrict__ uv,
                     float* __restrict__ scale_out) {
    const float* W  = (blockIdx.x == 0) ? Wk : Wv;
    const float* u0 = (blockIdx.x == 0) ? uk : uv;
    int tid = threadIdx.x;       // 0..1023 = d
    int lane = tid & 63;
    int wid = tid >> 6;          // 0..15
    __shared__ float u_s[N_DIM];
    __shared__ float v_s[D_DIM];
    __shared__ float t_s[N_DIM];
    __shared__ float red[16];
    __shared__ float bcs;
    if (tid < N_DIM) u_s[tid] = u0[tid];
    __syncthreads();
    for (int iter = 0; iter < 3; ++iter) {
        float acc = 0.f;
        #pragma unroll
        for (int nn = 0; nn < N_DIM; ++nn)
            acc += W[nn * D_DIM + tid] * u_s[nn];
        float ss = acc * acc;
        #pragma unroll
        for (int o = 32; o > 0; o >>= 1) ss += __shfl_xor(ss, o, 64);
        if (lane == 0) red[wid] = ss;
        __syncthreads();
        if (tid == 0) {
            float tot = 0.f;
            #pragma unroll
            for (int w2 = 0; w2 < 16; ++w2) tot += red[w2];
            bcs = 1.0f / (sqrtf(tot) + EPS);
        }
        __syncthreads();
        v_s[tid] = acc * bcs;
        __syncthreads();
        #pragma unroll
        for (int rr = 0; rr < 4; ++rr) {
            int r = wid * 4 + rr;
            float a = 0.f;
            #pragma unroll
            for (int e = 0; e < 16; ++e)
                a += W[r * D_DIM + lane + 64 * e] * v_s[lane + 64 * e];
            #pragma unroll
            for (int o = 32; o > 0; o >>= 1) a += __shfl_xor(a, o, 64);
            if (lane == 0) t_s[r] = a;
        }
        __syncthreads();
        if (wid == 0) {
            float uu = t_s[lane];
            float s2 = uu * uu;
            #pragma unroll
            for (int o = 32; o > 0; o >>= 1) s2 += __shfl_xor(s2, o, 64);
            float inv = 1.0f / (sqrtf(__shfl(s2, 0, 64)) + EPS);
            u_s[lane] = uu * inv;
        }
        __syncthreads();
    }
    if (wid == 0) {
        float val = t_s[lane] * u_s[lane];
        #pragma unroll
        for (int o = 32; o > 0; o >>= 1) val += __shfl_xor(val, o, 64);
        if (lane == 0) scale_out[blockIdx.x] = RADIUS / (fabsf(val) + EPS);
    }
}

// ------- build bf16 hi/lo of fused scaled W in MFMA-FRAGMENT-MAJOR order -------
// idx = g*16384 + s64*1024 + kk*512 + (flh*16 + fl)*8 + e  (proven absmax 1.0)
__global__ __launch_bounds__(256)
void build_wt_kernel(const float* __restrict__ Wk,
                     const float* __restrict__ Wv,
                     const float* __restrict__ Wq,
                     const float* __restrict__ scale,
                     unsigned short* __restrict__ BPh,
                     unsigned short* __restrict__ BPl) {
    int c = blockIdx.x;           // 0..191 (output col)
    int tid = threadIdx.x;        // 0..255, 4 k-values each
    const float* src;
    float sc;
    if (c < 64)       { src = Wk + (size_t)c * D_DIM;         sc = scale[0]; }
    else if (c < 128) { src = Wv + (size_t)(c - 64) * D_DIM;  sc = scale[1]; }
    else              { src = Wq + (size_t)(c - 128) * D_DIM; sc = 1.0f; }
    int g = c >> 4;
    int fl = c & 15;
    float4 w = *(const float4*)(src + tid * 4);
    float vals[4] = {w.x * sc, w.y * sc, w.z * sc, w.w * sc};
    #pragma unroll
    for (int e4 = 0; e4 < 4; ++e4) {
        int k = tid * 4 + e4;
        unsigned short h = f2bf(vals[e4]);
        unsigned short l = f2bf(vals[e4] - bf2f(h));
        int s  = k >> 6;
        int kk = (k >> 5) & 1;
        int flh = (k >> 3) & 3;
        int e  = k & 7;
        size_t idx = (size_t)g * 16384 + s * 1024 + kk * 512 + (flh * 16 + fl) * 8 + e;
        BPh[idx] = h;
        BPl[idx] = l;
    }
}

// ------------- projections via split-bf16 MFMA -------------
// 8 x 128-k stages, double-buffered LDS, depth-2 x prefetch riding across
// counted barriers (no vmcnt drain).
#define PBM 32
#define KSTAGE 128
__global__ __launch_bounds__(256)
void proj_mfma_kernel(const float* __restrict__ x,
                      const unsigned short* __restrict__ BPh,
                      const unsigned short* __restrict__ BPl,
                      float* __restrict__ kvq) {
    __shared__ __align__(16) unsigned short ldsA[2][2][PBM * KSTAGE];  // 32 KB
    int tid = threadIdx.x;
    int lane = tid & 63;
    int wv = tid >> 6;                 // 0..3 -> cols [wv*48, +48)
    int fl15 = lane & 15;
    int flh = lane >> 4;               // 0..3
    int rowBase = blockIdx.x * PBM;

    int r_st = tid >> 3;
    int sub  = tid & 7;
    const float* xrow = x + (size_t)(rowBase + r_st) * D_DIM + sub * 8;
    int wb0 = r_st * 256 + ((sub * 16) ^ ((r_st & 7) << 4));
    int wb1 = wb0 + 128;

    const unsigned short* bbh = BPh + (size_t)(wv * 3) * 16384 + lane * 8;
    const unsigned short* bbl = BPl + (size_t)(wv * 3) * 16384 + lane * 8;

    f32x4 acc[2][3];
    #pragma unroll
    for (int mt = 0; mt < 2; ++mt)
        #pragma unroll
        for (int nt = 0; nt < 3; ++nt) acc[mt][nt] = (f32x4)(0.f);

    // prologue: stage 0 -> buf0; stage 1 -> regs p*
    {
        float4 c0 = *(const float4*)(xrow);
        float4 c1 = *(const float4*)(xrow + 4);
        float4 c2 = *(const float4*)(xrow + 64);
        float4 c3 = *(const float4*)(xrow + 68);
        float v0[8] = {c0.x, c0.y, c0.z, c0.w, c1.x, c1.y, c1.z, c1.w};
        float v1[8] = {c2.x, c2.y, c2.z, c2.w, c3.x, c3.y, c3.z, c3.w};
        short8 h0, l0, h1, l1;
        #pragma unroll
        for (int e = 0; e < 8; ++e) {
            unsigned short hh = f2bf(v0[e]);
            h0[e] = (short)hh; l0[e] = (short)f2bf(v0[e] - bf2f(hh));
            hh = f2bf(v1[e]);
            h1[e] = (short)hh; l1[e] = (short)f2bf(v1[e] - bf2f(hh));
        }
        char* pH = (char*)&ldsA[0][0][0];
        char* pL = (char*)&ldsA[0][1][0];
        *(short8*)(pH + wb0) = h0; *(short8*)(pL + wb0) = l0;
        *(short8*)(pH + wb1) = h1; *(short8*)(pL + wb1) = l1;
    }
    float4 p0 = *(const float4*)(xrow + KSTAGE);
    float4 p1 = *(const float4*)(xrow + KSTAGE + 4);
    float4 p2 = *(const float4*)(xrow + KSTAGE + 64);
    float4 p3 = *(const float4*)(xrow + KSTAGE + 68);
    bar_lgkm();

    #pragma unroll 1
    for (int qt = 0; qt < 8; ++qt) {
        int buf = qt & 1;
        // depth-2: issue loads for stage qt+2
        float4 q0, q1, q2, q3;
        if (qt < 6) {
            const float* nx = xrow + (qt + 2) * KSTAGE;
            q0 = *(const float4*)(nx);
            q1 = *(const float4*)(nx + 4);
            q2 = *(const float4*)(nx + 64);
            q3 = *(const float4*)(nx + 68);
        }
        const char* pH = (const char*)&ldsA[buf][0][0];
        const char* pL = (const char*)&ldsA[buf][1][0];
        #pragma unroll
        for (int s = 0; s < 2; ++s) {
            int sg = qt * 2 + s;
            short8 bh[2][3], bl[2][3];
            #pragma unroll
            for (int nt = 0; nt < 3; ++nt)
                #pragma unroll
                for (int kk = 0; kk < 2; ++kk) {
                    size_t off = (size_t)nt * 16384 + sg * 1024 + kk * 512;
                    bh[kk][nt] = *(const short8*)(bbh + off);
                    bl[kk][nt] = *(const short8*)(bbl + off);
                }
            #pragma unroll
            for (int kk = 0; kk < 2; ++kk) {
                short8 ah[2], al[2];
                #pragma unroll
                for (int mt = 0; mt < 2; ++mt) {
                    int row = mt * 16 + fl15;
                    int off = row * 256 + s * 128 +
                              ((kk * 64 + flh * 16) ^ ((row & 7) << 4));
                    ah[mt] = *(const short8*)(pH + off);
                    al[mt] = *(const short8*)(pL + off);
                }
                #pragma unroll
                for (int mt = 0; mt < 2; ++mt)
                    #pragma unroll
                    for (int nt = 0; nt < 3; ++nt) {
                        acc[mt][nt] = __builtin_amdgcn_mfma_f32_16x16x32_bf16(
                            ah[mt], bh[kk][nt], acc[mt][nt], 0, 0, 0);
                        acc[mt][nt] = __builtin_amdgcn_mfma_f32_16x16x32_bf16(
                            ah[mt], bl[kk][nt], acc[mt][nt], 0, 0, 0);
                        acc[mt][nt] = __builtin_amdgcn_mfma_f32_16x16x32_bf16(
                            al[mt], bh[kk][nt], acc[mt][nt], 0, 0, 0);
                    }
            }
        }
        // convert stage qt+1 (regs p*) and write into the other buffer
        if (qt < 7) {
            float v0[8] = {p0.x, p0.y, p0.z, p0.w, p1.x, p1.y, p1.z, p1.w};
            float v1[8] = {p2.x, p2.y, p2.z, p2.w, p3.x, p3.y, p3.z, p3.w};
            short8 h0, l0, h1, l1;
            #pragma unroll
            for (int e = 0; e < 8; ++e) {
                unsigned short hh = f2bf(v0[e]);
                h0[e] = (short)hh; l0[e] = (short)f2bf(v0[e] - bf2f(hh));
                hh = f2bf(v1[e]);
                h1[e] = (short)hh; l1[e] = (short)f2bf(v1[e] - bf2f(hh));
            }
            char* qH = (char*)&ldsA[buf ^ 1][0][0];
            char* qL = (char*)&ldsA[buf ^ 1][1][0];
            *(short8*)(qH + wb0) = h0; *(short8*)(qL + wb0) = l0;
            *(short8*)(qH + wb1) = h1; *(short8*)(qL + wb1) = l1;
        }
        bar_lgkm();
        p0 = q0; p1 = q1; p2 = q2; p3 = q3;
    }

    #pragma unroll
    for (int mt = 0; mt < 2; ++mt)
        #pragma unroll
        for (int nt = 0; nt < 3; ++nt) {
            int col = wv * 48 + nt * 16 + fl15;
            #pragma unroll
            for (int r = 0; r < 4; ++r) {
                int row = rowBase + mt * 16 + flh * 4 + r;
                kvq[(size_t)row * 192 + col] = acc[mt][nt][r];
            }
        }
}

// ------------- carry init: S_init[c] = scan of full previous chunk (window 128) -------------
__global__ __launch_bounds__(256)
void carry_init_kernel(const float* __restrict__ kvq,
                       float* __restrict__ S_init) {
    int blk = blockIdx.x;          // 0..479
    int c   = (blk >> 5) + 1;      // 1..15
    int rem = blk & 31;
    int b   = rem >> 2;
    int iq  = rem & 3;
    int i   = iq * 16 + (threadIdx.x >> 4);
    int j4  = (threadIdx.x & 15) * 4;
    int tp  = (c - 1) * CHUNK_LEN;
    float4 s4 = {0.f, 0.f, 0.f, 0.f};
    #pragma unroll 4
    for (int u = 0; u < CHUNK_LEN; ++u) {
        const float* base = kvq + (size_t)((tp + u) * B_DIM + b) * 192;
        float v = base[64 + i];
        float4 k4 = *(const float4*)(base + j4);
        s4.x = __builtin_fmaf(DECAY, s4.x, v * k4.x);
        s4.y = __builtin_fmaf(DECAY, s4.y, v * k4.y);
        s4.z = __builtin_fmaf(DECAY, s4.z, v * k4.z);
        s4.w = __builtin_fmaf(DECAY, s4.w, v * k4.w);
    }
    *(float4*)&S_init[(((size_t)c * B_DIM + b) * 64 + i) * 64 + j4] = s4;
}

// ------------- scan: lane = (r,jq) holds S[i0+r][4jq..+3]; dwordx4 NT stores -------------
// 512 blocks = (c,b,ig); 4 waves/block; wave covers rows i0 = ig*16+widL*4 .. +3.
#define SC_TILE 8
__global__ __launch_bounds__(256)
void scan_kernel(const float* __restrict__ kvq,
                 const float* __restrict__ S_init,
                 const float* __restrict__ S0,
                 float* __restrict__ out,      // [T,B,n]
                 float* __restrict__ S_all) {  // [T+1,B,n,n]
    __shared__ __align__(16) float P[4][SC_TILE][4][20];   // stride 20: aligned + spread
    int widL = threadIdx.x >> 6;
    int lane = threadIdx.x & 63;
    int r  = lane >> 4;          // row within wave's 4
    int jq = lane & 15;          // col quad
    int blk = blockIdx.x;
    int c  = blk >> 5;           // 0..15
    int b  = (blk >> 2) & 7;
    int ig = blk & 3;
    int i0 = ig * 16 + widL * 4;
    int i  = i0 + r;

    // reduce-phase lane mapping
    int pp   = lane >> 1;        // 0..31
    int ur   = pp >> 2;          // u slot 0..7
    int rr   = pp & 3;           // row slot
    int half = lane & 1;

    // S0 row copy (c==0 blocks cover all (b,i))
    if (c == 0) {
        f32x4 s0v = *(const f32x4*)&S0[((size_t)b * 64 + i) * 64 + jq * 4];
        *(f32x4*)&S_all[(size_t)b * 4096 + (size_t)i * 64 + jq * 4] = s0v;
    }

    f32x4 s = (f32x4)(0.f);
    if (c > 0)
        s = *(const f32x4*)&S_init[(((size_t)c * B_DIM + b) * 64 + i) * 64 + jq * 4];

    int t0 = c * CHUNK_LEN;
    for (int tb = 0; tb < CHUNK_LEN; tb += SC_TILE) {
        #pragma unroll
        for (int u = 0; u < SC_TILE; ++u) {
            int t = t0 + tb + u;
            const float* base = kvq + (size_t)(t * B_DIM + b) * 192;
            f32x4 k4 = *(const f32x4*)(base + jq * 4);
            f32x4 q4 = *(const f32x4*)(base + 128 + jq * 4);
            float v  = base[64 + i];
            s.x = __builtin_fmaf(DECAY, s.x, v * k4.x);
            s.y = __builtin_fmaf(DECAY, s.y, v * k4.y);
            s.z = __builtin_fmaf(DECAY, s.z, v * k4.z);
            s.w = __builtin_fmaf(DECAY, s.w, v * k4.w);
            __builtin_nontemporal_store(
                s, (f32x4*)&S_all[((size_t)(t + 1) * B_DIM + b) * 4096 +
                                  (size_t)i * 64 + jq * 4]);
            P[widL][u][r][jq] = s.x * q4.x + s.y * q4.y + s.z * q4.z + s.w * q4.w;
        }
        // wave-private reduce: lane (ur,rr,half) sums 8 partials + 1 shuffle
        const float* pr = &P[widL][ur][rr][half * 8];
        f32x4 a0 = *(const f32x4*)pr;
        f32x4 a1 = *(const f32x4*)(pr + 4);
        float acc = (a0.x + a0.y) + (a0.z + a0.w) + (a1.x + a1.y) + (a1.z + a1.w);
        acc += __shfl_xor(acc, 1, 64);
        if (half == 0) {
            int t = t0 + tb + ur;
            float sg = 1.0f / (1.0f + __expf(-acc));
            out[((size_t)t * B_DIM + b) * 64 + i0 + rr] = acc * acc * sg;
        }
    }
}

extern "C" void kernel_launch(void* const* d_in, const int* in_sizes, int n_in,
                              void* d_out, int out_size, void* d_ws, size_t ws_size,
                              hipStream_t stream) {
    const float* x  = (const float*)d_in[0];
    const float* S0 = (const float*)d_in[1];
    const float* Wk = (const float*)d_in[2];
    const float* Wv = (const float*)d_in[3];
    const float* Wq = (const float*)d_in[4];
    const float* uk = (const float*)d_in[5];
    const float* uv = (const float*)d_in[6];

    float* out   = (float*)d_out;                              // [T,B,n]
    float* S_all = out + (size_t)T_DIM * B_DIM * N_DIM;        // [T+1,B,n,n]

    float* ws    = (float*)d_ws;
    float* scale = ws;                                   // 2 floats (pad 64)
    float* kvq   = ws + 64;                              // 16384*192
    unsigned short* BPh = (unsigned short*)(kvq + (size_t)16384 * 192);  // 192*1024
    unsigned short* BPl = BPh + (size_t)192 * D_DIM;
    float* S_init = (float*)(BPl + (size_t)192 * D_DIM); // 16*8*64*64 floats

    spectral_kernel<<<2, 1024, 0, stream>>>(Wk, Wv, uk, uv, scale);
    build_wt_kernel<<<192, 256, 0, stream>>>(Wk, Wv, Wq, scale, BPh, BPl);
    proj_mfma_kernel<<<T_DIM * B_DIM / PBM, 256, 0, stream>>>(x, BPh, BPl, kvq);
    carry_init_kernel<<<(NCHUNK - 1) * 32, 256, 0, stream>>>(kvq, S_init);
    scan_kernel<<<NCHUNK * B_DIM * 4, 256, 0, stream>>>(kvq, S_init, S0, out, S_all);
}